// Round 7
// baseline (152.003 us; speedup 1.0000x reference)
//
#include <hip/hip_runtime.h>
#include <hip/hip_bf16.h>

#define Bv 32
#define Dv 512
#define Kv 64
#define Nv 1024
#define EPSv 1e-12f

typedef __attribute__((ext_vector_type(8))) short bf16x8;
typedef __attribute__((ext_vector_type(4))) float f32x4;

// fp32 -> bf16 (RNE), bit-level
__device__ __forceinline__ unsigned short f2b(float f) {
  union { float f; unsigned u; } v; v.f = f;
  unsigned r = v.u + 0x7fffu + ((v.u >> 16) & 1u);
  return (unsigned short)(r >> 16);
}
__device__ __forceinline__ unsigned pack2(float a, float b) {
  return (unsigned)f2b(a) | ((unsigned)f2b(b) << 16);
}

// ---------------------------------------------------------------------------
// Kernel X (R12): streaming fp32->bf16 convert of x into the TILED xbf
// layout (xbf[(b*16+nt)*32768 + d*64 + nl]), plus w-convert and asum/colsq
// zeroing folded into 16 tail blocks. Barrier-free, fire-and-forget stores,
// high occupancy -> pure BW (~96 MB -> ~15 us). This removes the 25-us
// writeback anomaly measured when the same bytes were written from inside
// the barrier-phased fused_scores (R9/R11: ~40 us vs R6 no-writeback ~15).
// Grid 8208 x 256.
// ---------------------------------------------------------------------------
__global__ __launch_bounds__(256) void xconv(
    const float* __restrict__ x, unsigned short* __restrict__ xbf,
    const float* __restrict__ w, unsigned short* __restrict__ wbf,
    float* __restrict__ zbuf) {
  const int blk = blockIdx.x;
  if (blk >= 8192) {   // w-convert (K*D = 32768 floats) + zero asum/colsq
    int id = (blk - 8192) * 256 + threadIdx.x;   // 0..4095
    int i = id * 8;
    float4 a = *(const float4*)&w[i];
    float4 c = *(const float4*)&w[i + 4];
    uint4 o;
    o.x = pack2(a.x, a.y); o.y = pack2(a.z, a.w);
    o.z = pack2(c.x, c.y); o.w = pack2(c.z, c.w);
    *(uint4*)&wbf[i] = o;
    if (id < 2 * Bv * Kv) zbuf[id] = 0.f;
    return;
  }
  // x: 16,777,216 floats; 8192 blocks x 256 thr x 8 floats.
  // id -> (b, d, n8): n fastest => wave reads 2KB contiguous.
  size_t id = (size_t)blk * 256 + threadIdx.x;
  int n8 = (int)(id & 127);
  int d  = (int)((id >> 7) & 511);
  int b  = (int)(id >> 16);
  int nf = n8 * 8;
  const float* src = x + ((size_t)b * Dv + d) * Nv + nf;
  float4 a = *(const float4*)src;
  float4 c = *(const float4*)(src + 4);
  uint4 o;
  o.x = pack2(a.x, a.y); o.y = pack2(a.z, a.w);
  o.z = pack2(c.x, c.y); o.w = pack2(c.z, c.w);
  int nt = nf >> 6;    // tile index
  int nl = nf & 63;    // n within tile
  *(uint4*)&xbf[((size_t)b * 16 + nt) * (Dv * 64) + (size_t)d * 64 + nl] = o;
}

// ---------------------------------------------------------------------------
// Kernel 1 (fused T+A), R12 = R6's verified writeback-free body (inferred
// ~15 us) with R9's TILED assign writes. Reads fp32 x (cold HBM, 64 MB),
// stages LDS xT with the rotation bank-fix, scores GEMM + softmax, writes
// tiled assign + asum atomics. NO xbf writeback (xconv owns that now).
// Grid (N/64, B) = (16, 32) = 512 blocks, 512 threads (8 waves), 2 blk/CU.
// ---------------------------------------------------------------------------
__global__ __launch_bounds__(512) void fused_scores(
    const float* __restrict__ x, const unsigned short* __restrict__ wbf,
    unsigned short* __restrict__ assign, float* __restrict__ asum) {
  __shared__ unsigned short xT[64 * 520];   // [n][d], pitch 520 shorts (1040B)
  __shared__ float redmax[4][64];
  __shared__ float redsum[4][64];

  const int t = threadIdx.x;   // 0..511
  const int b = blockIdx.y;
  const int nt = blockIdx.x;
  const int n0 = nt * 64;

  // ---------------- staging ----------------
  {
    const int lo = t & 15;     // n-quad
    const int hi = t >> 4;     // 0..31 (d-pair subindex)
    const int s = (lo >> 1) & 3;   // write-rotation amount (bank spread)
    const float* xb = x + (size_t)b * Dv * Nv + n0;
#pragma unroll
    for (int r = 0; r < 8; r++) {
      int d = (hi + 32 * r) * 2;        // even d row; covers 0..510
      int n4 = lo * 4;
      float4 v0 = *(const float4*)&xb[(size_t)d * Nv + n4];
      float4 v1 = *(const float4*)&xb[(size_t)(d + 1) * Nv + n4];
      // LDS xT: dword at [n][d] = (x[d][n], x[d+1][n]); d even -> aligned
      unsigned w0 = pack2(v0.x, v1.x);
      unsigned w1 = pack2(v0.y, v1.y);
      unsigned w2 = pack2(v0.z, v1.z);
      unsigned w3 = pack2(v0.w, v1.w);
      // rotate data+row-offset by s: instruction j writes row n4+((j+s)&3)
      unsigned a0 = (s & 1) ? w1 : w0, a1 = (s & 1) ? w2 : w1,
               a2 = (s & 1) ? w3 : w2, a3 = (s & 1) ? w0 : w3;
      unsigned b0 = (s & 2) ? a2 : a0, b1 = (s & 2) ? a3 : a1,
               b2 = (s & 2) ? a0 : a2, b3 = (s & 2) ? a1 : a3;
      *(unsigned*)&xT[(n4 + ((0 + s) & 3)) * 520 + d] = b0;
      *(unsigned*)&xT[(n4 + ((1 + s) & 3)) * 520 + d] = b1;
      *(unsigned*)&xT[(n4 + ((2 + s) & 3)) * 520 + d] = b2;
      *(unsigned*)&xT[(n4 + ((3 + s) & 3)) * 520 + d] = b3;
    }
  }
  __syncthreads();

  // ---------------- scores GEMM ----------------
  const int wv = t >> 6;        // 0..7
  const int lane = t & 63;
  const int q = lane >> 4;
  const int m = lane & 15;
  const int k16 = wv & 3;       // k-tile
  const int nsub = wv >> 2;     // n-half: cols [nsub*32, +32)

  f32x4 acc0 = {0.f, 0.f, 0.f, 0.f};
  f32x4 acc1 = {0.f, 0.f, 0.f, 0.f};

  const unsigned short* wp = wbf + (size_t)(k16 * 16 + m) * Dv + q * 8;
  const unsigned short* l0 = &xT[(nsub * 32 + m) * 520 + q * 8];
  const unsigned short* l1 = l0 + 16 * 520;

#pragma unroll
  for (int d0 = 0; d0 < Dv; d0 += 32) {
    bf16x8 af = *(const bf16x8*)(wp + d0);
    bf16x8 bf0 = *(const bf16x8*)(l0 + d0);
    bf16x8 bf1 = *(const bf16x8*)(l1 + d0);
    acc0 = __builtin_amdgcn_mfma_f32_16x16x32_bf16(af, bf0, acc0, 0, 0, 0);
    acc1 = __builtin_amdgcn_mfma_f32_16x16x32_bf16(af, bf1, acc1, 0, 0, 0);
  }

  // ---------------- softmax over k (64) ----------------
  float m0 = fmaxf(fmaxf(acc0[0], acc0[1]), fmaxf(acc0[2], acc0[3]));
  float m1 = fmaxf(fmaxf(acc1[0], acc1[1]), fmaxf(acc1[2], acc1[3]));
  m0 = fmaxf(m0, __shfl_xor(m0, 16)); m0 = fmaxf(m0, __shfl_xor(m0, 32));
  m1 = fmaxf(m1, __shfl_xor(m1, 16)); m1 = fmaxf(m1, __shfl_xor(m1, 32));
  if (q == 0) {
    redmax[k16][nsub * 32 + m] = m0;
    redmax[k16][nsub * 32 + 16 + m] = m1;
  }
  __syncthreads();
  const int c0 = nsub * 32 + m, c1 = c0 + 16;
  float mc0 = fmaxf(fmaxf(redmax[0][c0], redmax[1][c0]), fmaxf(redmax[2][c0], redmax[3][c0]));
  float mc1 = fmaxf(fmaxf(redmax[0][c1], redmax[1][c1]), fmaxf(redmax[2][c1], redmax[3][c1]));

  float e0[4], e1[4];
  float s0 = 0.f, s1 = 0.f;
#pragma unroll
  for (int r = 0; r < 4; r++) {
    e0[r] = __expf(acc0[r] - mc0); s0 += e0[r];
    e1[r] = __expf(acc1[r] - mc1); s1 += e1[r];
  }
  s0 += __shfl_xor(s0, 16); s0 += __shfl_xor(s0, 32);
  s1 += __shfl_xor(s1, 16); s1 += __shfl_xor(s1, 32);
  if (q == 0) {
    redsum[k16][c0] = s0;
    redsum[k16][c1] = s1;
  }
  __syncthreads();
  float sc0 = 1.0f / (redsum[0][c0] + redsum[1][c0] + redsum[2][c0] + redsum[3][c0]);
  float sc1 = 1.0f / (redsum[0][c1] + redsum[1][c1] + redsum[2][c1] + redsum[3][c1]);

  // ---------------- assign write (tiled) + asum ----------------
  unsigned short* at_ = assign + ((size_t)b * 16 + nt) * (Kv * 64)
                        + (size_t)(k16 * 16 + q * 4) * 64 + nsub * 32;
#pragma unroll
  for (int r = 0; r < 4; r++) {
    float v0 = e0[r] * sc0;
    float v1 = e1[r] * sc1;
    at_[r * 64 + m] = f2b(v0);
    at_[r * 64 + 16 + m] = f2b(v1);
    float p = v0 + v1;
    p += __shfl_xor(p, 1); p += __shfl_xor(p, 2);
    p += __shfl_xor(p, 4); p += __shfl_xor(p, 8);
    if (m == 0) atomicAdd(&asum[b * Kv + k16 * 16 + q * 4 + r], p);
  }
}

// ---------------------------------------------------------------------------
// Kernel 2 — unchanged from R11: tiled bf16 reads (xbf L3-warm, written by
// xconv), depth-8 prefetch, bijective XCD swizzle (all 32 d-blocks of one b
// on the same XCD -> assign[b]+xbf[b] L2-shared).
// ---------------------------------------------------------------------------
__global__ __launch_bounds__(512, 2) void vlad_mfma(
    const unsigned short* __restrict__ xbf, const unsigned short* __restrict__ assign,
    const float* __restrict__ centers, const float* __restrict__ asum,
    float* __restrict__ vlad, float* __restrict__ colsq) {
  __shared__ float sred[4][64][4];   // [ksub][lane][r] from nh==1 waves

  const int t = threadIdx.x;
  const int flat = blockIdx.x;       // 0..1023
  const int loc = flat >> 3;         // 0..127
  const int b = ((loc >> 5) << 3) + (flat & 7);   // 0..31, co-XCD per b
  const int d0 = (loc & 31) * 16;
  const int wv = t >> 6;
  const int ksub = wv & 3;
  const int nh = wv >> 2;            // n-half: tiles nh*8 .. nh*8+7
  const int lane = t & 63;
  const int q = lane >> 4;
  const int m = lane & 15;
  const int k16 = ksub * 16;

  // group g (0..15): tile = g>>1, chunk = g&1
  const unsigned short* xp = xbf + ((size_t)b * 16 + nh * 8) * (Dv * 64)
                             + (size_t)(d0 + m) * 64 + q * 8;
  const unsigned short* ap = assign + ((size_t)b * 16 + nh * 8) * (Kv * 64)
                             + (size_t)(k16 + m) * 64 + q * 8;

  f32x4 acc = {0.f, 0.f, 0.f, 0.f};
  bf16x8 xv[8], av[8];

  // prologue: 16 loads in flight (groups 0..7)
#pragma unroll
  for (int i = 0; i < 8; i++) {
    xv[i] = *(const bf16x8*)(xp + (i >> 1) * (Dv * 64) + (i & 1) * 32);
    av[i] = *(const bf16x8*)(ap + (i >> 1) * (Kv * 64) + (i & 1) * 32);
  }
  __builtin_amdgcn_sched_barrier(0);

  // steady: consume group i, refill slot with group i+8
#pragma unroll
  for (int i = 0; i < 8; i++) {
    acc = __builtin_amdgcn_mfma_f32_16x16x32_bf16(xv[i], av[i], acc, 0, 0, 0);
    xv[i] = *(const bf16x8*)(xp + ((i + 8) >> 1) * (Dv * 64) + (i & 1) * 32);
    av[i] = *(const bf16x8*)(ap + ((i + 8) >> 1) * (Kv * 64) + (i & 1) * 32);
    __builtin_amdgcn_sched_barrier(0);
  }

  // drain
#pragma unroll
  for (int i = 0; i < 8; i++)
    acc = __builtin_amdgcn_mfma_f32_16x16x32_bf16(xv[i], av[i], acc, 0, 0, 0);

  if (nh == 1) {
#pragma unroll
    for (int r = 0; r < 4; r++) sred[ksub][lane][r] = acc[r];
  }
  __syncthreads();
  if (nh == 0) {
    const int k = k16 + m;
    const float as = asum[b * Kv + k];
    float ss = 0.f;
#pragma unroll
    for (int r = 0; r < 4; r++) {
      float v = acc[r] + sred[ksub][lane][r];
      int d = d0 + q * 4 + r;
      float val = v - centers[d * Kv + k] * as;
      vlad[((size_t)b * Dv + d) * Kv + k] = val;
      ss = fmaf(val, val, ss);
    }
    ss += __shfl_xor(ss, 16);
    ss += __shfl_xor(ss, 32);
    if (q == 0) atomicAdd(&colsq[b * Kv + k], ss);
  }
}

// ---------------------------------------------------------------------------
// Kernel D: out = vlad * colscale[b,k] * bscale[b]; float4-vectorized
// (16 B/lane). Grid 1024 x 256.
// ---------------------------------------------------------------------------
__global__ __launch_bounds__(256) void scale_kernel(
    const float* __restrict__ vlad, const float* __restrict__ colsq,
    float* __restrict__ out) {
  const int t = threadIdx.x;
  const size_t i = ((size_t)blockIdx.x * 256 + t) * 4;
  const int b = (int)(i >> 15);  // D*K = 32768 per b
  __shared__ float scs[64];
  __shared__ float bsh;
  if (t < 64) {
    float tot = colsq[b * Kv + t];
    float sc = 1.0f / fmaxf(sqrtf(tot), EPSv);
    scs[t] = sc;
    float contrib = tot * sc * sc;
#pragma unroll
    for (int off = 32; off > 0; off >>= 1) contrib += __shfl_down(contrib, off);
    if (t == 0) bsh = 1.0f / fmaxf(sqrtf(contrib), EPSv);
  }
  __syncthreads();
  float4 v = *(const float4*)&vlad[i];
  const int k = (int)(i & 63);          // 4-aligned, same b for all 4
  float4 o;
  o.x = v.x * scs[k + 0] * bsh;
  o.y = v.y * scs[k + 1] * bsh;
  o.z = v.z * scs[k + 2] * bsh;
  o.w = v.w * scs[k + 3] * bsh;
  *(float4*)&out[i] = o;
}

extern "C" void kernel_launch(void* const* d_in, const int* in_sizes, int n_in,
                              void* d_out, int out_size, void* d_ws, size_t ws_size,
                              hipStream_t stream) {
  const float* x = (const float*)d_in[0];        // [B, D, N]
  const float* w = (const float*)d_in[1];        // [K, D]
  const float* centers = (const float*)d_in[2];  // [D, K]
  float* out = (float*)d_out;                    // [B, D*K]

  char* ws = (char*)d_ws;
  unsigned short* assign = (unsigned short*)ws;               // tiled, 4 MB
  float* vlad = (float*)(ws + 4194304);                       // [B][D][K] fp32, 4 MB
  unsigned short* xbf = (unsigned short*)(ws + 8388608);      // tiled bf16, 32 MB
  unsigned short* wbf = (unsigned short*)(ws + 41943040);     // [K][D] bf16, 64 KB
  float* asum = (float*)(ws + 42008576);                      // B*K
  float* colsq = asum + Bv * Kv;                              // B*K (contiguous)

  xconv<<<8208, 256, 0, stream>>>(x, xbf, w, wbf, asum);  // also zeros asum+colsq
  fused_scores<<<dim3(Nv / 64, Bv), 512, 0, stream>>>(x, wbf, assign, asum);
  vlad_mfma<<<1024, 512, 0, stream>>>(xbf, assign, centers, asum, vlad, colsq);
  scale_kernel<<<1024, 256, 0, stream>>>(vlad, colsq, out);
}

// Round 8
// 144.340 us; speedup vs baseline: 1.0531x; 1.0531x over previous
//
#include <hip/hip_runtime.h>
#include <hip/hip_bf16.h>

#define Bv 32
#define Dv 512
#define Kv 64
#define Nv 1024
#define EPSv 1e-12f

typedef __attribute__((ext_vector_type(8))) short bf16x8;
typedef __attribute__((ext_vector_type(4))) float f32x4;

// fp32 -> bf16 (RNE), bit-level
__device__ __forceinline__ unsigned short f2b(float f) {
  union { float f; unsigned u; } v; v.f = f;
  unsigned r = v.u + 0x7fffu + ((v.u >> 16) & 1u);
  return (unsigned short)(r >> 16);
}
__device__ __forceinline__ unsigned pack2(float a, float b) {
  return (unsigned)f2b(a) | ((unsigned)f2b(b) << 16);
}

// ---------------------------------------------------------------------------
// Kernel W: convert conv_w (K x D fp32) -> bf16, AND zero asum+colsq.
// 32 blocks x 256 thr.  (R11 config — verified 143.5us total.)
// ---------------------------------------------------------------------------
__global__ __launch_bounds__(256) void wconv(const float* __restrict__ w,
                                             unsigned short* __restrict__ wbf,
                                             float* __restrict__ zbuf) {
  int id = blockIdx.x * 256 + threadIdx.x;
  int i = id * 4;
  float4 v = *(const float4*)&w[i];
  uint2 o = make_uint2(pack2(v.x, v.y), pack2(v.z, v.w));
  *(uint2*)&wbf[i] = o;
  if (id < 2 * Bv * Kv) zbuf[id] = 0.f;   // asum (B*K) + colsq (B*K) contiguous
}

// ---------------------------------------------------------------------------
// Kernel 1 (fused T+A) — byte-identical to R11 (verified):
// tiled xbf writeback + tiled assign + LDS rotation bank-fix.
// Grid (N/64, B) = (16, 32) = 512 blocks, 512 threads (8 waves), 2 blk/CU.
// ---------------------------------------------------------------------------
__global__ __launch_bounds__(512) void fused_scores(
    const float* __restrict__ x, const unsigned short* __restrict__ wbf,
    unsigned short* __restrict__ xbf, unsigned short* __restrict__ assign,
    float* __restrict__ asum) {
  __shared__ unsigned short xT[64 * 520];   // [n][d], pitch 520 shorts (1040B)
  __shared__ float redmax[4][64];
  __shared__ float redsum[4][64];

  const int t = threadIdx.x;   // 0..511
  const int b = blockIdx.y;
  const int nt = blockIdx.x;
  const int n0 = nt * 64;

  // ---------------- staging (+ tiled xbf writeback) ----------------
  {
    const int lo = t & 15;     // n-quad
    const int hi = t >> 4;     // 0..31 (d-pair subindex)
    const int s = (lo >> 1) & 3;   // write-rotation amount (bank spread)
    const float* xb = x + (size_t)b * Dv * Nv + n0;
    unsigned short* xt = xbf + ((size_t)b * 16 + nt) * (Dv * 64);
#pragma unroll
    for (int r = 0; r < 8; r++) {
      int d = (hi + 32 * r) * 2;        // even d row; covers 0..510
      int n4 = lo * 4;
      float4 v0 = *(const float4*)&xb[(size_t)d * Nv + n4];
      float4 v1 = *(const float4*)&xb[(size_t)(d + 1) * Nv + n4];
      // tiled xbf write: row-major within 64KB tile, dense windows
      *(uint2*)&xt[(size_t)d * 64 + n4] =
          make_uint2(pack2(v0.x, v0.y), pack2(v0.z, v0.w));
      *(uint2*)&xt[(size_t)(d + 1) * 64 + n4] =
          make_uint2(pack2(v1.x, v1.y), pack2(v1.z, v1.w));
      // LDS xT: dword at [n][d] = (x[d][n], x[d+1][n]); d even -> aligned
      unsigned w0 = pack2(v0.x, v1.x);
      unsigned w1 = pack2(v0.y, v1.y);
      unsigned w2 = pack2(v0.z, v1.z);
      unsigned w3 = pack2(v0.w, v1.w);
      // rotate data+row-offset by s: instruction j writes row n4+((j+s)&3)
      unsigned a0 = (s & 1) ? w1 : w0, a1 = (s & 1) ? w2 : w1,
               a2 = (s & 1) ? w3 : w2, a3 = (s & 1) ? w0 : w3;
      unsigned b0 = (s & 2) ? a2 : a0, b1 = (s & 2) ? a3 : a1,
               b2 = (s & 2) ? a0 : a2, b3 = (s & 2) ? a1 : a3;
      *(unsigned*)&xT[(n4 + ((0 + s) & 3)) * 520 + d] = b0;
      *(unsigned*)&xT[(n4 + ((1 + s) & 3)) * 520 + d] = b1;
      *(unsigned*)&xT[(n4 + ((2 + s) & 3)) * 520 + d] = b2;
      *(unsigned*)&xT[(n4 + ((3 + s) & 3)) * 520 + d] = b3;
    }
  }
  __syncthreads();

  // ---------------- scores GEMM ----------------
  const int wv = t >> 6;        // 0..7
  const int lane = t & 63;
  const int q = lane >> 4;
  const int m = lane & 15;
  const int k16 = wv & 3;       // k-tile
  const int nsub = wv >> 2;     // n-half: cols [nsub*32, +32)

  f32x4 acc0 = {0.f, 0.f, 0.f, 0.f};
  f32x4 acc1 = {0.f, 0.f, 0.f, 0.f};

  const unsigned short* wp = wbf + (size_t)(k16 * 16 + m) * Dv + q * 8;
  const unsigned short* l0 = &xT[(nsub * 32 + m) * 520 + q * 8];
  const unsigned short* l1 = l0 + 16 * 520;

#pragma unroll
  for (int d0 = 0; d0 < Dv; d0 += 32) {
    bf16x8 af = *(const bf16x8*)(wp + d0);
    bf16x8 bf0 = *(const bf16x8*)(l0 + d0);
    bf16x8 bf1 = *(const bf16x8*)(l1 + d0);
    acc0 = __builtin_amdgcn_mfma_f32_16x16x32_bf16(af, bf0, acc0, 0, 0, 0);
    acc1 = __builtin_amdgcn_mfma_f32_16x16x32_bf16(af, bf1, acc1, 0, 0, 0);
  }

  // ---------------- softmax over k (64) ----------------
  float m0 = fmaxf(fmaxf(acc0[0], acc0[1]), fmaxf(acc0[2], acc0[3]));
  float m1 = fmaxf(fmaxf(acc1[0], acc1[1]), fmaxf(acc1[2], acc1[3]));
  m0 = fmaxf(m0, __shfl_xor(m0, 16)); m0 = fmaxf(m0, __shfl_xor(m0, 32));
  m1 = fmaxf(m1, __shfl_xor(m1, 16)); m1 = fmaxf(m1, __shfl_xor(m1, 32));
  if (q == 0) {
    redmax[k16][nsub * 32 + m] = m0;
    redmax[k16][nsub * 32 + 16 + m] = m1;
  }
  __syncthreads();
  const int c0 = nsub * 32 + m, c1 = c0 + 16;
  float mc0 = fmaxf(fmaxf(redmax[0][c0], redmax[1][c0]), fmaxf(redmax[2][c0], redmax[3][c0]));
  float mc1 = fmaxf(fmaxf(redmax[0][c1], redmax[1][c1]), fmaxf(redmax[2][c1], redmax[3][c1]));

  float e0[4], e1[4];
  float s0 = 0.f, s1 = 0.f;
#pragma unroll
  for (int r = 0; r < 4; r++) {
    e0[r] = __expf(acc0[r] - mc0); s0 += e0[r];
    e1[r] = __expf(acc1[r] - mc1); s1 += e1[r];
  }
  s0 += __shfl_xor(s0, 16); s0 += __shfl_xor(s0, 32);
  s1 += __shfl_xor(s1, 16); s1 += __shfl_xor(s1, 32);
  if (q == 0) {
    redsum[k16][c0] = s0;
    redsum[k16][c1] = s1;
  }
  __syncthreads();
  float sc0 = 1.0f / (redsum[0][c0] + redsum[1][c0] + redsum[2][c0] + redsum[3][c0]);
  float sc1 = 1.0f / (redsum[0][c1] + redsum[1][c1] + redsum[2][c1] + redsum[3][c1]);

  // ---------------- assign write (tiled) + asum ----------------
  unsigned short* at_ = assign + ((size_t)b * 16 + nt) * (Kv * 64)
                        + (size_t)(k16 * 16 + q * 4) * 64 + nsub * 32;
#pragma unroll
  for (int r = 0; r < 4; r++) {
    float v0 = e0[r] * sc0;
    float v1 = e1[r] * sc1;
    at_[r * 64 + m] = f2b(v0);
    at_[r * 64 + 16 + m] = f2b(v1);
    float p = v0 + v1;
    p += __shfl_xor(p, 1); p += __shfl_xor(p, 2);
    p += __shfl_xor(p, 4); p += __shfl_xor(p, 8);
    if (m == 0) atomicAdd(&asum[b * Kv + k16 * 16 + q * 4 + r], p);
  }
}

// ---------------------------------------------------------------------------
// Kernel 2 (R13): same dataflow/layout as R11 (tiled xbf+assign, XCD
// swizzle) but the load pipeline is now ASM-VOLATILE global_load_dwordx4
// with hand-counted s_waitcnt vmcnt(N) + sched_barrier(0) (rule #18) —
// the compiler provably destroyed every source-level prefetch (VGPR=32 in
// R7/R8). 16 loads permanently in flight per wave; waits only drain the
// oldest 2 (vmcnt(14)), never 0 until the final drain steps.
// ---------------------------------------------------------------------------
__global__ __launch_bounds__(512, 2) void vlad_mfma(
    const unsigned short* __restrict__ xbf, const unsigned short* __restrict__ assign,
    const float* __restrict__ centers, const float* __restrict__ asum,
    float* __restrict__ vlad, float* __restrict__ colsq) {
  __shared__ float sred[4][64][4];   // [ksub][lane][r] from nh==1 waves

  const int t = threadIdx.x;
  const int flat = blockIdx.x;       // 0..1023
  const int loc = flat >> 3;         // 0..127
  const int b = ((loc >> 5) << 3) + (flat & 7);   // 0..31, co-XCD per b
  const int d0 = (loc & 31) * 16;
  const int wv = t >> 6;
  const int ksub = wv & 3;
  const int nh = wv >> 2;            // n-half: tiles nh*8 .. nh*8+7
  const int lane = t & 63;
  const int q = lane >> 4;
  const int m = lane & 15;
  const int k16 = ksub * 16;

  // group g (0..15): tile = g>>1, chunk = g&1
  const unsigned short* xp = xbf + ((size_t)b * 16 + nh * 8) * (Dv * 64)
                             + (size_t)(d0 + m) * 64 + q * 8;
  const unsigned short* ap = assign + ((size_t)b * 16 + nh * 8) * (Kv * 64)
                             + (size_t)(k16 + m) * 64 + q * 8;

  f32x4 acc = {0.f, 0.f, 0.f, 0.f};
  bf16x8 xv[8], av[8];

#define ISSUE(slot, g)                                                        \
  {                                                                           \
    const unsigned short* _xa = xp + ((g) >> 1) * (Dv * 64) + ((g) & 1) * 32; \
    const unsigned short* _aa = ap + ((g) >> 1) * (Kv * 64) + ((g) & 1) * 32; \
    asm volatile("global_load_dwordx4 %0, %1, off"                            \
                 : "=v"(xv[slot]) : "v"(_xa));                                \
    asm volatile("global_load_dwordx4 %0, %1, off"                            \
                 : "=v"(av[slot]) : "v"(_aa));                                \
  }

#define STEP(g)                                                               \
  asm volatile("s_waitcnt vmcnt(14)");                                        \
  __builtin_amdgcn_sched_barrier(0);                                          \
  acc = __builtin_amdgcn_mfma_f32_16x16x32_bf16(xv[g], av[g], acc, 0, 0, 0);  \
  ISSUE(g, (g) + 8);                                                          \
  __builtin_amdgcn_sched_barrier(0);

#define DRAIN(g, NLIT)                                                        \
  asm volatile("s_waitcnt vmcnt(" NLIT ")");                                  \
  __builtin_amdgcn_sched_barrier(0);                                          \
  acc = __builtin_amdgcn_mfma_f32_16x16x32_bf16(xv[g], av[g], acc, 0, 0, 0);

  // prologue: 16 loads in flight (groups 0..7)
  ISSUE(0, 0) ISSUE(1, 1) ISSUE(2, 2) ISSUE(3, 3)
  ISSUE(4, 4) ISSUE(5, 5) ISSUE(6, 6) ISSUE(7, 7)
  __builtin_amdgcn_sched_barrier(0);

  // steady: consume group g (oldest 2), reissue group g+8 into slot g
  STEP(0) STEP(1) STEP(2) STEP(3) STEP(4) STEP(5) STEP(6) STEP(7)

  // drain: slots 0..7 hold groups 8..15; outstanding 16,14,12,...
  DRAIN(0, "14") DRAIN(1, "12") DRAIN(2, "10") DRAIN(3, "8")
  DRAIN(4, "6")  DRAIN(5, "4")  DRAIN(6, "2")  DRAIN(7, "0")

#undef ISSUE
#undef STEP
#undef DRAIN

  if (nh == 1) {
#pragma unroll
    for (int r = 0; r < 4; r++) sred[ksub][lane][r] = acc[r];
  }
  __syncthreads();
  if (nh == 0) {
    const int k = k16 + m;
    const float as = asum[b * Kv + k];
    float ss = 0.f;
#pragma unroll
    for (int r = 0; r < 4; r++) {
      float v = acc[r] + sred[ksub][lane][r];
      int d = d0 + q * 4 + r;
      float val = v - centers[d * Kv + k] * as;
      vlad[((size_t)b * Dv + d) * Kv + k] = val;
      ss = fmaf(val, val, ss);
    }
    ss += __shfl_xor(ss, 16);
    ss += __shfl_xor(ss, 32);
    if (q == 0) atomicAdd(&colsq[b * Kv + k], ss);
  }
}

// ---------------------------------------------------------------------------
// Kernel D: out = vlad * colscale[b,k] * bscale[b]; float4-vectorized
// (16 B/lane). Grid 1024 x 256.
// ---------------------------------------------------------------------------
__global__ __launch_bounds__(256) void scale_kernel(
    const float* __restrict__ vlad, const float* __restrict__ colsq,
    float* __restrict__ out) {
  const int t = threadIdx.x;
  const size_t i = ((size_t)blockIdx.x * 256 + t) * 4;
  const int b = (int)(i >> 15);  // D*K = 32768 per b
  __shared__ float scs[64];
  __shared__ float bsh;
  if (t < 64) {
    float tot = colsq[b * Kv + t];
    float sc = 1.0f / fmaxf(sqrtf(tot), EPSv);
    scs[t] = sc;
    float contrib = tot * sc * sc;
#pragma unroll
    for (int off = 32; off > 0; off >>= 1) contrib += __shfl_down(contrib, off);
    if (t == 0) bsh = 1.0f / fmaxf(sqrtf(contrib), EPSv);
  }
  __syncthreads();
  float4 v = *(const float4*)&vlad[i];
  const int k = (int)(i & 63);          // 4-aligned, same b for all 4
  float4 o;
  o.x = v.x * scs[k + 0] * bsh;
  o.y = v.y * scs[k + 1] * bsh;
  o.z = v.z * scs[k + 2] * bsh;
  o.w = v.w * scs[k + 3] * bsh;
  *(float4*)&out[i] = o;
}

extern "C" void kernel_launch(void* const* d_in, const int* in_sizes, int n_in,
                              void* d_out, int out_size, void* d_ws, size_t ws_size,
                              hipStream_t stream) {
  const float* x = (const float*)d_in[0];        // [B, D, N]
  const float* w = (const float*)d_in[1];        // [K, D]
  const float* centers = (const float*)d_in[2];  // [D, K]
  float* out = (float*)d_out;                    // [B, D*K]

  char* ws = (char*)d_ws;
  unsigned short* assign = (unsigned short*)ws;               // tiled, 4 MB
  float* vlad = (float*)(ws + 4194304);                       // [B][D][K] fp32, 4 MB
  unsigned short* xbf = (unsigned short*)(ws + 8388608);      // tiled bf16, 32 MB
  unsigned short* wbf = (unsigned short*)(ws + 41943040);     // [K][D] bf16, 64 KB
  float* asum = (float*)(ws + 42008576);                      // B*K
  float* colsq = asum + Bv * Kv;                              // B*K (contiguous)

  wconv<<<32, 256, 0, stream>>>(w, wbf, asum);   // also zeros asum+colsq
  fused_scores<<<dim3(Nv / 64, Bv), 512, 0, stream>>>(x, wbf, xbf, assign, asum);
  vlad_mfma<<<1024, 512, 0, stream>>>(xbf, assign, centers, asum, vlad, colsq);
  scale_kernel<<<1024, 256, 0, stream>>>(vlad, colsq, out);
}

// Round 9
// 131.593 us; speedup vs baseline: 1.1551x; 1.0969x over previous
//
#include <hip/hip_runtime.h>
#include <hip/hip_bf16.h>

#define Bv 32
#define Dv 512
#define Kv 64
#define Nv 1024
#define EPSv 1e-12f

typedef __attribute__((ext_vector_type(8))) short bf16x8;
typedef __attribute__((ext_vector_type(4))) float f32x4;

// fp32 -> bf16 (RNE), bit-level
__device__ __forceinline__ unsigned short f2b(float f) {
  union { float f; unsigned u; } v; v.f = f;
  unsigned r = v.u + 0x7fffu + ((v.u >> 16) & 1u);
  return (unsigned short)(r >> 16);
}
__device__ __forceinline__ unsigned pack2(float a, float b) {
  return (unsigned)f2b(a) | ((unsigned)f2b(b) << 16);
}

// global -> LDS direct copy, 16B per lane, no dest VGPRs (deep MLP).
#define GLOAD_LDS16(gsrc, ldst)                                             \
  __builtin_amdgcn_global_load_lds(                                         \
      (const __attribute__((address_space(1))) void*)(gsrc),                \
      (__attribute__((address_space(3))) void*)(ldst), 16, 0, 0)

// ---------------------------------------------------------------------------
// Kernel W: convert conv_w (K x D fp32) -> bf16, AND zero asum+colsq.
// ---------------------------------------------------------------------------
__global__ __launch_bounds__(256) void wconv(const float* __restrict__ w,
                                             unsigned short* __restrict__ wbf,
                                             float* __restrict__ zbuf) {
  int id = blockIdx.x * 256 + threadIdx.x;
  int i = id * 4;
  float4 v = *(const float4*)&w[i];
  uint2 o = make_uint2(pack2(v.x, v.y), pack2(v.z, v.w));
  *(uint2*)&wbf[i] = o;
  if (id < 2 * Bv * Kv) zbuf[id] = 0.f;   // asum (B*K) + colsq (B*K)
}

// ---------------------------------------------------------------------------
// Kernel 1 (fused T+A) — R11 body (verified), grid now 1D with XCD
// co-location: all 16 n-tiles of batch b run on XCD b%8, so b's xbf+assign
// are WRITTEN into the same L2 that vlad_stage/combine (same swizzle) read.
// ---------------------------------------------------------------------------
__global__ __launch_bounds__(512) void fused_scores(
    const float* __restrict__ x, const unsigned short* __restrict__ wbf,
    unsigned short* __restrict__ xbf, unsigned short* __restrict__ assign,
    float* __restrict__ asum) {
  __shared__ unsigned short xT[64 * 520];   // [n][d], pitch 520 shorts
  __shared__ float redmax[4][64];
  __shared__ float redsum[4][64];

  const int t = threadIdx.x;   // 0..511
  // co-XCD decode: xcd = flat&7 hosts b in {xcd, xcd+8, xcd+16, xcd+24}
  const int flat = blockIdx.x;            // 0..511
  const int i0 = flat >> 3;               // 0..63
  const int b = (flat & 7) + 8 * (i0 & 3);
  const int nt = i0 >> 2;                 // 0..15
  const int n0 = nt * 64;

  // ---------------- staging (+ tiled xbf writeback) ----------------
  {
    const int lo = t & 15;
    const int hi = t >> 4;
    const int s = (lo >> 1) & 3;
    const float* xb = x + (size_t)b * Dv * Nv + n0;
    unsigned short* xt = xbf + ((size_t)b * 16 + nt) * (Dv * 64);
#pragma unroll
    for (int r = 0; r < 8; r++) {
      int d = (hi + 32 * r) * 2;
      int n4 = lo * 4;
      float4 v0 = *(const float4*)&xb[(size_t)d * Nv + n4];
      float4 v1 = *(const float4*)&xb[(size_t)(d + 1) * Nv + n4];
      *(uint2*)&xt[(size_t)d * 64 + n4] =
          make_uint2(pack2(v0.x, v0.y), pack2(v0.z, v0.w));
      *(uint2*)&xt[(size_t)(d + 1) * 64 + n4] =
          make_uint2(pack2(v1.x, v1.y), pack2(v1.z, v1.w));
      unsigned w0 = pack2(v0.x, v1.x);
      unsigned w1 = pack2(v0.y, v1.y);
      unsigned w2 = pack2(v0.z, v1.z);
      unsigned w3 = pack2(v0.w, v1.w);
      unsigned a0 = (s & 1) ? w1 : w0, a1 = (s & 1) ? w2 : w1,
               a2 = (s & 1) ? w3 : w2, a3 = (s & 1) ? w0 : w3;
      unsigned b0 = (s & 2) ? a2 : a0, b1 = (s & 2) ? a3 : a1,
               b2 = (s & 2) ? a0 : a2, b3 = (s & 2) ? a1 : a3;
      *(unsigned*)&xT[(n4 + ((0 + s) & 3)) * 520 + d] = b0;
      *(unsigned*)&xT[(n4 + ((1 + s) & 3)) * 520 + d] = b1;
      *(unsigned*)&xT[(n4 + ((2 + s) & 3)) * 520 + d] = b2;
      *(unsigned*)&xT[(n4 + ((3 + s) & 3)) * 520 + d] = b3;
    }
  }
  __syncthreads();

  // ---------------- scores GEMM ----------------
  const int wv = t >> 6;
  const int lane = t & 63;
  const int q = lane >> 4;
  const int m = lane & 15;
  const int k16 = wv & 3;
  const int nsub = wv >> 2;

  f32x4 acc0 = {0.f, 0.f, 0.f, 0.f};
  f32x4 acc1 = {0.f, 0.f, 0.f, 0.f};

  const unsigned short* wp = wbf + (size_t)(k16 * 16 + m) * Dv + q * 8;
  const unsigned short* l0 = &xT[(nsub * 32 + m) * 520 + q * 8];
  const unsigned short* l1 = l0 + 16 * 520;

#pragma unroll
  for (int d0 = 0; d0 < Dv; d0 += 32) {
    bf16x8 af = *(const bf16x8*)(wp + d0);
    bf16x8 bf0 = *(const bf16x8*)(l0 + d0);
    bf16x8 bf1 = *(const bf16x8*)(l1 + d0);
    acc0 = __builtin_amdgcn_mfma_f32_16x16x32_bf16(af, bf0, acc0, 0, 0, 0);
    acc1 = __builtin_amdgcn_mfma_f32_16x16x32_bf16(af, bf1, acc1, 0, 0, 0);
  }

  // ---------------- softmax over k (64) ----------------
  float m0 = fmaxf(fmaxf(acc0[0], acc0[1]), fmaxf(acc0[2], acc0[3]));
  float m1 = fmaxf(fmaxf(acc1[0], acc1[1]), fmaxf(acc1[2], acc1[3]));
  m0 = fmaxf(m0, __shfl_xor(m0, 16)); m0 = fmaxf(m0, __shfl_xor(m0, 32));
  m1 = fmaxf(m1, __shfl_xor(m1, 16)); m1 = fmaxf(m1, __shfl_xor(m1, 32));
  if (q == 0) {
    redmax[k16][nsub * 32 + m] = m0;
    redmax[k16][nsub * 32 + 16 + m] = m1;
  }
  __syncthreads();
  const int c0 = nsub * 32 + m, c1 = c0 + 16;
  float mc0 = fmaxf(fmaxf(redmax[0][c0], redmax[1][c0]), fmaxf(redmax[2][c0], redmax[3][c0]));
  float mc1 = fmaxf(fmaxf(redmax[0][c1], redmax[1][c1]), fmaxf(redmax[2][c1], redmax[3][c1]));

  float e0[4], e1[4];
  float s0 = 0.f, s1 = 0.f;
#pragma unroll
  for (int r = 0; r < 4; r++) {
    e0[r] = __expf(acc0[r] - mc0); s0 += e0[r];
    e1[r] = __expf(acc1[r] - mc1); s1 += e1[r];
  }
  s0 += __shfl_xor(s0, 16); s0 += __shfl_xor(s0, 32);
  s1 += __shfl_xor(s1, 16); s1 += __shfl_xor(s1, 32);
  if (q == 0) {
    redsum[k16][c0] = s0;
    redsum[k16][c1] = s1;
  }
  __syncthreads();
  float sc0 = 1.0f / (redsum[0][c0] + redsum[1][c0] + redsum[2][c0] + redsum[3][c0]);
  float sc1 = 1.0f / (redsum[0][c1] + redsum[1][c1] + redsum[2][c1] + redsum[3][c1]);

  unsigned short* at_ = assign + ((size_t)b * 16 + nt) * (Kv * 64)
                        + (size_t)(k16 * 16 + q * 4) * 64 + nsub * 32;
#pragma unroll
  for (int r = 0; r < 4; r++) {
    float v0 = e0[r] * sc0;
    float v1 = e1[r] * sc1;
    at_[r * 64 + m] = f2b(v0);
    at_[r * 64 + 16 + m] = f2b(v1);
    float p = v0 + v1;
    p += __shfl_xor(p, 1); p += __shfl_xor(p, 2);
    p += __shfl_xor(p, 4); p += __shfl_xor(p, 8);
    if (m == 0) atomicAdd(&asum[b * Kv + k16 * 16 + q * 4 + r], p);
  }
}

// ---------------------------------------------------------------------------
// Kernel 2 (R14): LDS-staged GEMM. Block = (b, 64-d group, n-half), 256 thr
// (4 waves = 4 d-stripes of 16). Double-buffered 8KB x-tile + 8KB a-tile via
// global_load_lds (NO dest VGPRs -> deep MLP; the fix for the ~30us
// MLP-capped VGPR-ring regime of R11/R13). Tiles are contiguous 8KB slabs of
// the tiled xbf/assign. Waves SHARE the LDS tiles -> logical traffic 256MB
// -> 64MB. ds_read frags are 2-way bank aliasing (free, m136).
// Writes per-half partials vpart[nh][b][d][k]; combine() finishes.
// Grid 512 (co-XCD with fused_scores), LDS 32KB -> 2 blk/CU.
// ---------------------------------------------------------------------------
__global__ __launch_bounds__(256) void vlad_stage(
    const unsigned short* __restrict__ xbf, const unsigned short* __restrict__ assign,
    float* __restrict__ vpart) {
  __shared__ unsigned short xs[2][64 * 64];   // [buf][d_local][n] 8KB each
  __shared__ unsigned short as_[2][64 * 64];  // [buf][k][n]

  const int t = threadIdx.x;
  const int flat = blockIdx.x;            // 0..511
  const int i0 = flat >> 3;               // 0..63
  const int b = (flat & 7) + 8 * (i0 & 3);
  const int j = i0 >> 2;                  // 0..15
  const int dg = j & 7;                   // 64-d group
  const int nh = j >> 3;                  // n-half: tiles nh*8..nh*8+7

  const int w = t >> 6;                   // wave 0..3 = d-stripe
  const int lane = t & 63;
  const int q = lane >> 4;
  const int m = lane & 15;

  const unsigned short* xsrc = xbf + ((size_t)b * 16 + nh * 8) * (Dv * 64)
                               + (size_t)dg * 64 * 64;     // 8KB slab / tile
  const unsigned short* asrc = assign + ((size_t)b * 16 + nh * 8) * (Kv * 64);

  // wave w stages bytes [w*2048, w*2048+2048) of each 8KB slab (2 instrs)
#define STAGE(buf, tt)                                                        \
  {                                                                           \
    const unsigned short* _xs = xsrc + (size_t)(tt) * (Dv * 64) + w * 1024;   \
    const unsigned short* _as = asrc + (size_t)(tt) * (Kv * 64) + w * 1024;   \
    unsigned short* _lx = &xs[buf][w * 1024];                                 \
    unsigned short* _la = &as_[buf][w * 1024];                                \
    GLOAD_LDS16(_xs + lane * 8, _lx);                                         \
    GLOAD_LDS16(_xs + 512 + lane * 8, _lx + 512);                             \
    GLOAD_LDS16(_as + lane * 8, _la);                                         \
    GLOAD_LDS16(_as + 512 + lane * 8, _la + 512);                             \
  }

  f32x4 acc0 = {0.f,0.f,0.f,0.f}, acc1 = {0.f,0.f,0.f,0.f};
  f32x4 acc2 = {0.f,0.f,0.f,0.f}, acc3 = {0.f,0.f,0.f,0.f};

  STAGE(0, 0)
  asm volatile("s_waitcnt vmcnt(0)");
  __syncthreads();

  int buf = 0;
#pragma unroll
  for (int tt = 0; tt < 8; tt++) {
    if (tt < 7) STAGE(buf ^ 1, tt + 1)
    // compute tile tt from buf
#pragma unroll
    for (int nc = 0; nc < 2; nc++) {
      bf16x8 xv = *(const bf16x8*)&xs[buf][(w * 16 + m) * 64 + nc * 32 + q * 8];
      bf16x8 a0 = *(const bf16x8*)&as_[buf][(0 * 16 + m) * 64 + nc * 32 + q * 8];
      bf16x8 a1 = *(const bf16x8*)&as_[buf][(1 * 16 + m) * 64 + nc * 32 + q * 8];
      bf16x8 a2 = *(const bf16x8*)&as_[buf][(2 * 16 + m) * 64 + nc * 32 + q * 8];
      bf16x8 a3 = *(const bf16x8*)&as_[buf][(3 * 16 + m) * 64 + nc * 32 + q * 8];
      acc0 = __builtin_amdgcn_mfma_f32_16x16x32_bf16(xv, a0, acc0, 0, 0, 0);
      acc1 = __builtin_amdgcn_mfma_f32_16x16x32_bf16(xv, a1, acc1, 0, 0, 0);
      acc2 = __builtin_amdgcn_mfma_f32_16x16x32_bf16(xv, a2, acc2, 0, 0, 0);
      acc3 = __builtin_amdgcn_mfma_f32_16x16x32_bf16(xv, a3, acc3, 0, 0, 0);
    }
    asm volatile("s_waitcnt vmcnt(0)");
    __syncthreads();
    buf ^= 1;
  }
#undef STAGE

  // partial write: d = dg*64 + w*16 + q*4 + r, k = ksub*16 + m
  float* vp = vpart + (((size_t)nh * Bv + b) * Dv + dg * 64 + w * 16) * Kv;
  f32x4 accs[4] = {acc0, acc1, acc2, acc3};
#pragma unroll
  for (int ks = 0; ks < 4; ks++)
#pragma unroll
    for (int r = 0; r < 4; r++)
      vp[(size_t)(q * 4 + r) * Kv + ks * 16 + m] = accs[ks][r];
}

// ---------------------------------------------------------------------------
// Kernel C (R14): vlad = h0 + h1 - centers*asum; colsq via LDS reduce.
// Each block: 1024 consecutive elements (one b, 16 d-rows, all 64 k).
// Grid 1024 x 256, float4 per thread. Streaming, ~12MB total.
// ---------------------------------------------------------------------------
__global__ __launch_bounds__(256) void combine(
    const float* __restrict__ vpart, const float* __restrict__ centers,
    const float* __restrict__ asum, float* __restrict__ vlad,
    float* __restrict__ colsq) {
  __shared__ float cacc[64];
  const int t = threadIdx.x;
  const int flat = blockIdx.x;            // 0..1023 ; co-XCD with producer
  const int i0 = flat >> 3;
  const int b = (flat & 7) + 8 * (i0 & 3);
  const int dblk = i0 >> 2;               // 0..31 (16-d slab)
  if (t < 64) cacc[t] = 0.f;
  __syncthreads();

  const size_t eb = ((size_t)b * Dv + dblk * 16) * Kv;  // block's element base
  const size_t i = eb + t * 4;
  const int d = (int)((i >> 6) & 511);
  const int k0 = (int)(i & 63);

  float4 h0 = *(const float4*)&vpart[i];
  float4 h1 = *(const float4*)&vpart[(size_t)Bv * Dv * Kv + i];
  float4 c = *(const float4*)&centers[d * Kv + k0];
  float4 av = *(const float4*)&asum[b * Kv + k0];
  float4 o;
  o.x = h0.x + h1.x - c.x * av.x;
  o.y = h0.y + h1.y - c.y * av.y;
  o.z = h0.z + h1.z - c.z * av.z;
  o.w = h0.w + h1.w - c.w * av.w;
  *(float4*)&vlad[i] = o;
  atomicAdd(&cacc[k0 + 0], o.x * o.x);
  atomicAdd(&cacc[k0 + 1], o.y * o.y);
  atomicAdd(&cacc[k0 + 2], o.z * o.z);
  atomicAdd(&cacc[k0 + 3], o.w * o.w);
  __syncthreads();
  if (t < 64) atomicAdd(&colsq[b * Kv + t], cacc[t]);
}

// ---------------------------------------------------------------------------
// Kernel D: out = vlad * colscale[b,k] * bscale[b]; float4-vectorized.
// ---------------------------------------------------------------------------
__global__ __launch_bounds__(256) void scale_kernel(
    const float* __restrict__ vlad, const float* __restrict__ colsq,
    float* __restrict__ out) {
  const int t = threadIdx.x;
  const size_t i = ((size_t)blockIdx.x * 256 + t) * 4;
  const int b = (int)(i >> 15);
  __shared__ float scs[64];
  __shared__ float bsh;
  if (t < 64) {
    float tot = colsq[b * Kv + t];
    float sc = 1.0f / fmaxf(sqrtf(tot), EPSv);
    scs[t] = sc;
    float contrib = tot * sc * sc;
#pragma unroll
    for (int off = 32; off > 0; off >>= 1) contrib += __shfl_down(contrib, off);
    if (t == 0) bsh = 1.0f / fmaxf(sqrtf(contrib), EPSv);
  }
  __syncthreads();
  float4 v = *(const float4*)&vlad[i];
  const int k = (int)(i & 63);
  float4 o;
  o.x = v.x * scs[k + 0] * bsh;
  o.y = v.y * scs[k + 1] * bsh;
  o.z = v.z * scs[k + 2] * bsh;
  o.w = v.w * scs[k + 3] * bsh;
  *(float4*)&out[i] = o;
}

extern "C" void kernel_launch(void* const* d_in, const int* in_sizes, int n_in,
                              void* d_out, int out_size, void* d_ws, size_t ws_size,
                              hipStream_t stream) {
  const float* x = (const float*)d_in[0];        // [B, D, N]
  const float* w = (const float*)d_in[1];        // [K, D]
  const float* centers = (const float*)d_in[2];  // [D, K]
  float* out = (float*)d_out;                    // [B, D*K]

  char* ws = (char*)d_ws;
  unsigned short* assign = (unsigned short*)ws;               // tiled, 4 MB
  float* vlad = (float*)(ws + 4194304);                       // [B][D][K] fp32, 4 MB
  unsigned short* xbf = (unsigned short*)(ws + 8388608);      // tiled bf16, 32 MB
  unsigned short* wbf = (unsigned short*)(ws + 41943040);     // [K][D] bf16, 64 KB
  float* asum = (float*)(ws + 42008576);                      // B*K
  float* colsq = asum + Bv * Kv;                              // B*K
  float* vpart = (float*)(ws + 42025088);                     // [2][B][D][K] fp32, 8 MB

  wconv<<<32, 256, 0, stream>>>(w, wbf, asum);   // also zeros asum+colsq
  fused_scores<<<512, 512, 0, stream>>>(x, wbf, xbf, assign, asum);
  vlad_stage<<<512, 256, 0, stream>>>(xbf, assign, vpart);
  combine<<<1024, 256, 0, stream>>>(vpart, centers, asum, vlad, colsq);
  scale_kernel<<<1024, 256, 0, stream>>>(vlad, colsq, out);
}

// Round 10
// 124.643 us; speedup vs baseline: 1.2195x; 1.0558x over previous
//
#include <hip/hip_runtime.h>
#include <hip/hip_bf16.h>

#define Bv 32
#define Dv 512
#define Kv 64
#define Nv 1024
#define EPSv 1e-12f

typedef __attribute__((ext_vector_type(8))) short bf16x8;
typedef __attribute__((ext_vector_type(4))) float f32x4;

// fp32 -> bf16 (RNE), bit-level
__device__ __forceinline__ unsigned short f2b(float f) {
  union { float f; unsigned u; } v; v.f = f;
  unsigned r = v.u + 0x7fffu + ((v.u >> 16) & 1u);
  return (unsigned short)(r >> 16);
}
__device__ __forceinline__ unsigned pack2(float a, float b) {
  return (unsigned)f2b(a) | ((unsigned)f2b(b) << 16);
}

// global -> LDS direct copy, 16B per lane, no dest VGPRs (deep MLP).
#define GLOAD_LDS16(gsrc, ldst)                                             \
  __builtin_amdgcn_global_load_lds(                                         \
      (const __attribute__((address_space(1))) void*)(gsrc),                \
      (__attribute__((address_space(3))) void*)(ldst), 16, 0, 0)

// ---------------------------------------------------------------------------
// Kernel W: convert conv_w (K x D fp32) -> bf16, AND zero asum+colsq.
// ---------------------------------------------------------------------------
__global__ __launch_bounds__(256) void wconv(const float* __restrict__ w,
                                             unsigned short* __restrict__ wbf,
                                             float* __restrict__ zbuf) {
  int id = blockIdx.x * 256 + threadIdx.x;
  int i = id * 4;
  float4 v = *(const float4*)&w[i];
  uint2 o = make_uint2(pack2(v.x, v.y), pack2(v.z, v.w));
  *(uint2*)&wbf[i] = o;
  if (id < 2 * Bv * Kv) zbuf[id] = 0.f;   // asum (B*K) + colsq (B*K)
}

// ---------------------------------------------------------------------------
// Kernel 1 (fused T+A) — byte-identical body to R14 (verified 131.6 total):
// tiled xbf+assign writeback, LDS rotation bank-fix, co-XCD 1D grid
// (all 16 n-tiles of b on XCD b%8; vlad_stage consumes on the same XCD).
// ---------------------------------------------------------------------------
__global__ __launch_bounds__(512) void fused_scores(
    const float* __restrict__ x, const unsigned short* __restrict__ wbf,
    unsigned short* __restrict__ xbf, unsigned short* __restrict__ assign,
    float* __restrict__ asum) {
  __shared__ unsigned short xT[64 * 520];   // [n][d], pitch 520 shorts
  __shared__ float redmax[4][64];
  __shared__ float redsum[4][64];

  const int t = threadIdx.x;   // 0..511
  const int flat = blockIdx.x;            // 0..511
  const int i0 = flat >> 3;               // 0..63
  const int b = (flat & 7) + 8 * (i0 & 3);
  const int nt = i0 >> 2;                 // 0..15
  const int n0 = nt * 64;

  // ---------------- staging (+ tiled xbf writeback) ----------------
  {
    const int lo = t & 15;
    const int hi = t >> 4;
    const int s = (lo >> 1) & 3;
    const float* xb = x + (size_t)b * Dv * Nv + n0;
    unsigned short* xt = xbf + ((size_t)b * 16 + nt) * (Dv * 64);
#pragma unroll
    for (int r = 0; r < 8; r++) {
      int d = (hi + 32 * r) * 2;
      int n4 = lo * 4;
      float4 v0 = *(const float4*)&xb[(size_t)d * Nv + n4];
      float4 v1 = *(const float4*)&xb[(size_t)(d + 1) * Nv + n4];
      *(uint2*)&xt[(size_t)d * 64 + n4] =
          make_uint2(pack2(v0.x, v0.y), pack2(v0.z, v0.w));
      *(uint2*)&xt[(size_t)(d + 1) * 64 + n4] =
          make_uint2(pack2(v1.x, v1.y), pack2(v1.z, v1.w));
      unsigned w0 = pack2(v0.x, v1.x);
      unsigned w1 = pack2(v0.y, v1.y);
      unsigned w2 = pack2(v0.z, v1.z);
      unsigned w3 = pack2(v0.w, v1.w);
      unsigned a0 = (s & 1) ? w1 : w0, a1 = (s & 1) ? w2 : w1,
               a2 = (s & 1) ? w3 : w2, a3 = (s & 1) ? w0 : w3;
      unsigned b0 = (s & 2) ? a2 : a0, b1 = (s & 2) ? a3 : a1,
               b2 = (s & 2) ? a0 : a2, b3 = (s & 2) ? a1 : a3;
      *(unsigned*)&xT[(n4 + ((0 + s) & 3)) * 520 + d] = b0;
      *(unsigned*)&xT[(n4 + ((1 + s) & 3)) * 520 + d] = b1;
      *(unsigned*)&xT[(n4 + ((2 + s) & 3)) * 520 + d] = b2;
      *(unsigned*)&xT[(n4 + ((3 + s) & 3)) * 520 + d] = b3;
    }
  }
  __syncthreads();

  // ---------------- scores GEMM ----------------
  const int wv = t >> 6;
  const int lane = t & 63;
  const int q = lane >> 4;
  const int m = lane & 15;
  const int k16 = wv & 3;
  const int nsub = wv >> 2;

  f32x4 acc0 = {0.f, 0.f, 0.f, 0.f};
  f32x4 acc1 = {0.f, 0.f, 0.f, 0.f};

  const unsigned short* wp = wbf + (size_t)(k16 * 16 + m) * Dv + q * 8;
  const unsigned short* l0 = &xT[(nsub * 32 + m) * 520 + q * 8];
  const unsigned short* l1 = l0 + 16 * 520;

#pragma unroll
  for (int d0 = 0; d0 < Dv; d0 += 32) {
    bf16x8 af = *(const bf16x8*)(wp + d0);
    bf16x8 bf0 = *(const bf16x8*)(l0 + d0);
    bf16x8 bf1 = *(const bf16x8*)(l1 + d0);
    acc0 = __builtin_amdgcn_mfma_f32_16x16x32_bf16(af, bf0, acc0, 0, 0, 0);
    acc1 = __builtin_amdgcn_mfma_f32_16x16x32_bf16(af, bf1, acc1, 0, 0, 0);
  }

  // ---------------- softmax over k (64) ----------------
  float m0 = fmaxf(fmaxf(acc0[0], acc0[1]), fmaxf(acc0[2], acc0[3]));
  float m1 = fmaxf(fmaxf(acc1[0], acc1[1]), fmaxf(acc1[2], acc1[3]));
  m0 = fmaxf(m0, __shfl_xor(m0, 16)); m0 = fmaxf(m0, __shfl_xor(m0, 32));
  m1 = fmaxf(m1, __shfl_xor(m1, 16)); m1 = fmaxf(m1, __shfl_xor(m1, 32));
  if (q == 0) {
    redmax[k16][nsub * 32 + m] = m0;
    redmax[k16][nsub * 32 + 16 + m] = m1;
  }
  __syncthreads();
  const int c0 = nsub * 32 + m, c1 = c0 + 16;
  float mc0 = fmaxf(fmaxf(redmax[0][c0], redmax[1][c0]), fmaxf(redmax[2][c0], redmax[3][c0]));
  float mc1 = fmaxf(fmaxf(redmax[0][c1], redmax[1][c1]), fmaxf(redmax[2][c1], redmax[3][c1]));

  float e0[4], e1[4];
  float s0 = 0.f, s1 = 0.f;
#pragma unroll
  for (int r = 0; r < 4; r++) {
    e0[r] = __expf(acc0[r] - mc0); s0 += e0[r];
    e1[r] = __expf(acc1[r] - mc1); s1 += e1[r];
  }
  s0 += __shfl_xor(s0, 16); s0 += __shfl_xor(s0, 32);
  s1 += __shfl_xor(s1, 16); s1 += __shfl_xor(s1, 32);
  if (q == 0) {
    redsum[k16][c0] = s0;
    redsum[k16][c1] = s1;
  }
  __syncthreads();
  float sc0 = 1.0f / (redsum[0][c0] + redsum[1][c0] + redsum[2][c0] + redsum[3][c0]);
  float sc1 = 1.0f / (redsum[0][c1] + redsum[1][c1] + redsum[2][c1] + redsum[3][c1]);

  unsigned short* at_ = assign + ((size_t)b * 16 + nt) * (Kv * 64)
                        + (size_t)(k16 * 16 + q * 4) * 64 + nsub * 32;
#pragma unroll
  for (int r = 0; r < 4; r++) {
    float v0 = e0[r] * sc0;
    float v1 = e1[r] * sc1;
    at_[r * 64 + m] = f2b(v0);
    at_[r * 64 + 16 + m] = f2b(v1);
    float p = v0 + v1;
    p += __shfl_xor(p, 1); p += __shfl_xor(p, 2);
    p += __shfl_xor(p, 4); p += __shfl_xor(p, 8);
    if (m == 0) atomicAdd(&asum[b * Kv + k16 * 16 + q * 4 + r], p);
  }
}

// ---------------------------------------------------------------------------
// Kernel 2 (R15): LDS-staged GEMM, full-n per block -> NO vpart/combine.
// Block = (b, dg) with dg in [0,16): 32-d stripe x all 64 k x all n.
// 256 thr / 4 waves = (dh = w&1: 16-d half) x (kh = w>>1: 32-k half).
// 8 stage rounds of a tile-PAIR (24KB): x-slab 2x4KB + a-slab 2x8KB,
// double-buffered (48KB LDS), via global_load_lds (deep MLP, R14-proven).
// T2 XOR-swizzle (rule #21 both-sides): staging pre-swizzles the GLOBAL
// source chunk (ch ^= row&7; LDS dest stays linear), compute reads apply
// the same XOR -> ds_read spreads over all 32 banks (was 2x conflicted).
// Epilogue: val = acc - centers*asum (asum ready), write vlad direct,
// colsq atomics. Grid 512 co-XCD with fused_scores.
// ---------------------------------------------------------------------------
__global__ __launch_bounds__(256) void vlad_stage(
    const unsigned short* __restrict__ xbf, const unsigned short* __restrict__ assign,
    const float* __restrict__ centers, const float* __restrict__ asum,
    float* __restrict__ vlad, float* __restrict__ colsq) {
  __shared__ unsigned short xs[2][2 * 2048];   // [buf][tile-pair slab] 8KB
  __shared__ unsigned short as_[2][2 * 4096];  // [buf][tile-pair slab] 16KB

  const int t = threadIdx.x;
  const int flat = blockIdx.x;            // 0..511
  const int i0 = flat >> 3;               // 0..63
  const int b = (flat & 7) + 8 * (i0 & 3);
  const int dg = i0 >> 2;                 // 0..15 -> d base dg*32

  const int w = t >> 6;                   // wave 0..3
  const int dh = w & 1;                   // 16-d half
  const int kh = w >> 1;                  // 32-k half
  const int lane = t & 63;
  const int q = lane >> 4;
  const int m = lane & 15;

  // staging lane constants: row-sub = lane>>3, swizzled chunk
  const int rs = lane >> 3;               // 0..7
  const int csw = (lane & 7) ^ (rs & 7);  // chunk ^ (row&7)

  const unsigned short* xbase = xbf + (size_t)b * 16 * (Dv * 64) + dg * 2048;
  const unsigned short* abase = assign + (size_t)b * 16 * (Kv * 64);

  // per-wave staging offsets (shorts)
  //  x-slab rows: w*8 + rs   (32 rows/tile, 64 shorts/row)
  //  a-slab rows: w*16 + rs and +8
#define STAGE(buf, rr)                                                        \
  {                                                                           \
    _Pragma("unroll")                                                         \
    for (int s = 0; s < 2; s++) {                                             \
      int tile = (rr) * 2 + s;                                                \
      const unsigned short* _xs = xbase + (size_t)tile * (Dv * 64)            \
                                  + (w * 8 + rs) * 64 + csw * 8;              \
      const unsigned short* _a1 = abase + (size_t)tile * (Kv * 64)            \
                                  + (w * 16 + rs) * 64 + csw * 8;             \
      GLOAD_LDS16(_xs, &xs[buf][s * 2048 + w * 512]);                         \
      GLOAD_LDS16(_a1, &as_[buf][s * 4096 + w * 1024]);                       \
      GLOAD_LDS16(_a1 + 512, &as_[buf][s * 4096 + w * 1024 + 512]);           \
    }                                                                         \
  }

  f32x4 acc0 = {0.f,0.f,0.f,0.f}, acc1 = {0.f,0.f,0.f,0.f};

  STAGE(0, 0)
  asm volatile("s_waitcnt vmcnt(0)");
  __syncthreads();

  int buf = 0;
#pragma unroll
  for (int rr = 0; rr < 8; rr++) {
    if (rr < 7) STAGE(buf ^ 1, rr + 1)
    // compute tile-pair from buf; swizzled read chunk = (nc*4+q)^(m&7)
#pragma unroll
    for (int s = 0; s < 2; s++) {
#pragma unroll
      for (int nc = 0; nc < 2; nc++) {
        const int cidx = (((nc * 4 + q) ^ (m & 7))) * 8;
        bf16x8 xv = *(const bf16x8*)&xs[buf][s * 2048 + (dh * 16 + m) * 64 + cidx];
        bf16x8 a0 = *(const bf16x8*)&as_[buf][s * 4096 + (kh * 32 + m) * 64 + cidx];
        bf16x8 a1 = *(const bf16x8*)&as_[buf][s * 4096 + (kh * 32 + 16 + m) * 64 + cidx];
        acc0 = __builtin_amdgcn_mfma_f32_16x16x32_bf16(xv, a0, acc0, 0, 0, 0);
        acc1 = __builtin_amdgcn_mfma_f32_16x16x32_bf16(xv, a1, acc1, 0, 0, 0);
      }
    }
    asm volatile("s_waitcnt vmcnt(0)");
    __syncthreads();
    buf ^= 1;
  }
#undef STAGE

  // epilogue: d = dg*32 + dh*16 + q*4 + r; k = kh*32 + {0,16} + m
  const int k0 = kh * 32 + m;
  const int k1 = k0 + 16;
  const float as0 = asum[b * Kv + k0];
  const float as1 = asum[b * Kv + k1];
  float ss0 = 0.f, ss1 = 0.f;
#pragma unroll
  for (int r = 0; r < 4; r++) {
    int d = dg * 32 + dh * 16 + q * 4 + r;
    float v0 = acc0[r] - centers[d * Kv + k0] * as0;
    float v1 = acc1[r] - centers[d * Kv + k1] * as1;
    vlad[((size_t)b * Dv + d) * Kv + k0] = v0;
    vlad[((size_t)b * Dv + d) * Kv + k1] = v1;
    ss0 = fmaf(v0, v0, ss0);
    ss1 = fmaf(v1, v1, ss1);
  }
  ss0 += __shfl_xor(ss0, 16); ss0 += __shfl_xor(ss0, 32);
  ss1 += __shfl_xor(ss1, 16); ss1 += __shfl_xor(ss1, 32);
  if (q == 0) {
    atomicAdd(&colsq[b * Kv + k0], ss0);
    atomicAdd(&colsq[b * Kv + k1], ss1);
  }
}

// ---------------------------------------------------------------------------
// Kernel D: out = vlad * colscale[b,k] * bscale[b]; float4-vectorized.
// ---------------------------------------------------------------------------
__global__ __launch_bounds__(256) void scale_kernel(
    const float* __restrict__ vlad, const float* __restrict__ colsq,
    float* __restrict__ out) {
  const int t = threadIdx.x;
  const size_t i = ((size_t)blockIdx.x * 256 + t) * 4;
  const int b = (int)(i >> 15);
  __shared__ float scs[64];
  __shared__ float bsh;
  if (t < 64) {
    float tot = colsq[b * Kv + t];
    float sc = 1.0f / fmaxf(sqrtf(tot), EPSv);
    scs[t] = sc;
    float contrib = tot * sc * sc;
#pragma unroll
    for (int off = 32; off > 0; off >>= 1) contrib += __shfl_down(contrib, off);
    if (t == 0) bsh = 1.0f / fmaxf(sqrtf(contrib), EPSv);
  }
  __syncthreads();
  float4 v = *(const float4*)&vlad[i];
  const int k = (int)(i & 63);
  float4 o;
  o.x = v.x * scs[k + 0] * bsh;
  o.y = v.y * scs[k + 1] * bsh;
  o.z = v.z * scs[k + 2] * bsh;
  o.w = v.w * scs[k + 3] * bsh;
  *(float4*)&out[i] = o;
}

extern "C" void kernel_launch(void* const* d_in, const int* in_sizes, int n_in,
                              void* d_out, int out_size, void* d_ws, size_t ws_size,
                              hipStream_t stream) {
  const float* x = (const float*)d_in[0];        // [B, D, N]
  const float* w = (const float*)d_in[1];        // [K, D]
  const float* centers = (const float*)d_in[2];  // [D, K]
  float* out = (float*)d_out;                    // [B, D*K]

  char* ws = (char*)d_ws;
  unsigned short* assign = (unsigned short*)ws;               // tiled, 4 MB
  float* vlad = (float*)(ws + 4194304);                       // [B][D][K] fp32, 4 MB
  unsigned short* xbf = (unsigned short*)(ws + 8388608);      // tiled bf16, 32 MB
  unsigned short* wbf = (unsigned short*)(ws + 41943040);     // [K][D] bf16, 64 KB
  float* asum = (float*)(ws + 42008576);                      // B*K
  float* colsq = asum + Bv * Kv;                              // B*K

  wconv<<<32, 256, 0, stream>>>(w, wbf, asum);   // also zeros asum+colsq
  fused_scores<<<512, 512, 0, stream>>>(x, wbf, xbf, assign, asum);
  vlad_stage<<<512, 256, 0, stream>>>(xbf, assign, centers, asum, vlad, colsq);
  scale_kernel<<<1024, 256, 0, stream>>>(vlad, colsq, out);
}

// Round 11
// 123.614 us; speedup vs baseline: 1.2297x; 1.0083x over previous
//
#include <hip/hip_runtime.h>
#include <hip/hip_bf16.h>

#define Bv 32
#define Dv 512
#define Kv 64
#define Nv 1024
#define EPSv 1e-12f

typedef __attribute__((ext_vector_type(8))) short bf16x8;
typedef __attribute__((ext_vector_type(4))) float f32x4;

// fp32 -> bf16 (RNE), bit-level
__device__ __forceinline__ unsigned short f2b(float f) {
  union { float f; unsigned u; } v; v.f = f;
  unsigned r = v.u + 0x7fffu + ((v.u >> 16) & 1u);
  return (unsigned short)(r >> 16);
}
__device__ __forceinline__ unsigned pack2(float a, float b) {
  return (unsigned)f2b(a) | ((unsigned)f2b(b) << 16);
}
// HW packed cvt, RNE — same rounding as f2b/pack2. lo = a, hi = b.
__device__ __forceinline__ unsigned cvtpk(float a, float b) {
  unsigned r;
  asm("v_cvt_pk_bf16_f32 %0, %1, %2" : "=v"(r) : "v"(a), "v"(b));
  return r;
}

// global -> LDS direct copy, 16B per lane, no dest VGPRs (deep MLP).
#define GLOAD_LDS16(gsrc, ldst)                                             \
  __builtin_amdgcn_global_load_lds(                                         \
      (const __attribute__((address_space(1))) void*)(gsrc),                \
      (__attribute__((address_space(3))) void*)(ldst), 16, 0, 0)

// ---------------------------------------------------------------------------
// Kernel W: convert conv_w (K x D fp32) -> bf16, AND zero asum+colsq.
// ---------------------------------------------------------------------------
__global__ __launch_bounds__(256) void wconv(const float* __restrict__ w,
                                             unsigned short* __restrict__ wbf,
                                             float* __restrict__ zbuf) {
  int id = blockIdx.x * 256 + threadIdx.x;
  int i = id * 4;
  float4 v = *(const float4*)&w[i];
  uint2 o = make_uint2(pack2(v.x, v.y), pack2(v.z, v.w));
  *(uint2*)&wbf[i] = o;
  if (id < 2 * Bv * Kv) zbuf[id] = 0.f;   // asum (B*K) + colsq (B*K)
}

// ---------------------------------------------------------------------------
// Kernel 1 (fused T+A), R16 = verified R12 no-writeback body (xbf round-trip
// eliminated: vlad_stage now stages native fp32 x itself). Tiled assign +
// LDS rotation bank-fix + co-XCD 1D grid kept.
// Grid 512 x 512 thr (8 waves), 2 blk/CU.
// ---------------------------------------------------------------------------
__global__ __launch_bounds__(512) void fused_scores(
    const float* __restrict__ x, const unsigned short* __restrict__ wbf,
    unsigned short* __restrict__ assign, float* __restrict__ asum) {
  __shared__ unsigned short xT[64 * 520];   // [n][d], pitch 520 shorts
  __shared__ float redmax[4][64];
  __shared__ float redsum[4][64];

  const int t = threadIdx.x;   // 0..511
  const int flat = blockIdx.x;            // 0..511
  const int i0 = flat >> 3;               // 0..63
  const int b = (flat & 7) + 8 * (i0 & 3);
  const int nt = i0 >> 2;                 // 0..15
  const int n0 = nt * 64;

  // ---------------- staging ----------------
  {
    const int lo = t & 15;
    const int hi = t >> 4;
    const int s = (lo >> 1) & 3;
    const float* xb = x + (size_t)b * Dv * Nv + n0;
#pragma unroll
    for (int r = 0; r < 8; r++) {
      int d = (hi + 32 * r) * 2;
      int n4 = lo * 4;
      float4 v0 = *(const float4*)&xb[(size_t)d * Nv + n4];
      float4 v1 = *(const float4*)&xb[(size_t)(d + 1) * Nv + n4];
      unsigned w0 = pack2(v0.x, v1.x);
      unsigned w1 = pack2(v0.y, v1.y);
      unsigned w2 = pack2(v0.z, v1.z);
      unsigned w3 = pack2(v0.w, v1.w);
      unsigned a0 = (s & 1) ? w1 : w0, a1 = (s & 1) ? w2 : w1,
               a2 = (s & 1) ? w3 : w2, a3 = (s & 1) ? w0 : w3;
      unsigned b0 = (s & 2) ? a2 : a0, b1 = (s & 2) ? a3 : a1,
               b2 = (s & 2) ? a0 : a2, b3 = (s & 2) ? a1 : a3;
      *(unsigned*)&xT[(n4 + ((0 + s) & 3)) * 520 + d] = b0;
      *(unsigned*)&xT[(n4 + ((1 + s) & 3)) * 520 + d] = b1;
      *(unsigned*)&xT[(n4 + ((2 + s) & 3)) * 520 + d] = b2;
      *(unsigned*)&xT[(n4 + ((3 + s) & 3)) * 520 + d] = b3;
    }
  }
  __syncthreads();

  // ---------------- scores GEMM ----------------
  const int wv = t >> 6;
  const int lane = t & 63;
  const int q = lane >> 4;
  const int m = lane & 15;
  const int k16 = wv & 3;
  const int nsub = wv >> 2;

  f32x4 acc0 = {0.f, 0.f, 0.f, 0.f};
  f32x4 acc1 = {0.f, 0.f, 0.f, 0.f};

  const unsigned short* wp = wbf + (size_t)(k16 * 16 + m) * Dv + q * 8;
  const unsigned short* l0 = &xT[(nsub * 32 + m) * 520 + q * 8];
  const unsigned short* l1 = l0 + 16 * 520;

#pragma unroll
  for (int d0 = 0; d0 < Dv; d0 += 32) {
    bf16x8 af = *(const bf16x8*)(wp + d0);
    bf16x8 bf0 = *(const bf16x8*)(l0 + d0);
    bf16x8 bf1 = *(const bf16x8*)(l1 + d0);
    acc0 = __builtin_amdgcn_mfma_f32_16x16x32_bf16(af, bf0, acc0, 0, 0, 0);
    acc1 = __builtin_amdgcn_mfma_f32_16x16x32_bf16(af, bf1, acc1, 0, 0, 0);
  }

  // ---------------- softmax over k (64) ----------------
  float m0 = fmaxf(fmaxf(acc0[0], acc0[1]), fmaxf(acc0[2], acc0[3]));
  float m1 = fmaxf(fmaxf(acc1[0], acc1[1]), fmaxf(acc1[2], acc1[3]));
  m0 = fmaxf(m0, __shfl_xor(m0, 16)); m0 = fmaxf(m0, __shfl_xor(m0, 32));
  m1 = fmaxf(m1, __shfl_xor(m1, 16)); m1 = fmaxf(m1, __shfl_xor(m1, 32));
  if (q == 0) {
    redmax[k16][nsub * 32 + m] = m0;
    redmax[k16][nsub * 32 + 16 + m] = m1;
  }
  __syncthreads();
  const int c0 = nsub * 32 + m, c1 = c0 + 16;
  float mc0 = fmaxf(fmaxf(redmax[0][c0], redmax[1][c0]), fmaxf(redmax[2][c0], redmax[3][c0]));
  float mc1 = fmaxf(fmaxf(redmax[0][c1], redmax[1][c1]), fmaxf(redmax[2][c1], redmax[3][c1]));

  float e0[4], e1[4];
  float s0 = 0.f, s1 = 0.f;
#pragma unroll
  for (int r = 0; r < 4; r++) {
    e0[r] = __expf(acc0[r] - mc0); s0 += e0[r];
    e1[r] = __expf(acc1[r] - mc1); s1 += e1[r];
  }
  s0 += __shfl_xor(s0, 16); s0 += __shfl_xor(s0, 32);
  s1 += __shfl_xor(s1, 16); s1 += __shfl_xor(s1, 32);
  if (q == 0) {
    redsum[k16][c0] = s0;
    redsum[k16][c1] = s1;
  }
  __syncthreads();
  float sc0 = 1.0f / (redsum[0][c0] + redsum[1][c0] + redsum[2][c0] + redsum[3][c0]);
  float sc1 = 1.0f / (redsum[0][c1] + redsum[1][c1] + redsum[2][c1] + redsum[3][c1]);

  unsigned short* at_ = assign + ((size_t)b * 16 + nt) * (Kv * 64)
                        + (size_t)(k16 * 16 + q * 4) * 64 + nsub * 32;
#pragma unroll
  for (int r = 0; r < 4; r++) {
    float v0 = e0[r] * sc0;
    float v1 = e1[r] * sc1;
    at_[r * 64 + m] = f2b(v0);
    at_[r * 64 + 16 + m] = f2b(v1);
    float p = v0 + v1;
    p += __shfl_xor(p, 1); p += __shfl_xor(p, 2);
    p += __shfl_xor(p, 4); p += __shfl_xor(p, 8);
    if (m == 0) atomicAdd(&asum[b * Kv + k16 * 16 + q * 4 + r], p);
  }
}

// ---------------------------------------------------------------------------
// Kernel 2 (R16): LDS-staged GEMM reading NATIVE fp32 x (no xbf!).
// Block = (b, dg): 32-d stripe x 64 k x all n. 256 thr / 4 waves =
// (dh = w&1) x (kh = w>>1). 8 rounds of a tile-pair:
//   x: fp32 [32d][64n] = 8KB/tile via global_load_lds (rows ARE native x
//      rows — no tiled-xbf needed); in-register v_cvt_pk_bf16_f32 (RNE,
//      bit-identical to f2b) before MFMA. 16 cvt / 8 MFMA per round: hidden.
//   a: bf16 tiled assign, byte-identical staging to R15 (verified).
// Both-sides XOR swizzle (rule #21): x chunk ^= row&7 (16 chunks/row fp32),
// a chunk ^= row&7 (8 chunks/row). LDS 64KB -> 2 blk/CU.
// Epilogue: vlad direct + colsq atomics (R15-proven). Grid 512 co-XCD.
// ---------------------------------------------------------------------------
__global__ __launch_bounds__(256) void vlad_stage(
    const float* __restrict__ x, const unsigned short* __restrict__ assign,
    const float* __restrict__ centers, const float* __restrict__ asum,
    float* __restrict__ vlad, float* __restrict__ colsq) {
  __shared__ float xsf[2][2][2048];            // [buf][tile][32d x 64n] 8KB
  __shared__ unsigned short as_[2][2][4096];   // [buf][tile][64k x 64n] 8KB

  const int t = threadIdx.x;
  const int flat = blockIdx.x;            // 0..511
  const int i0 = flat >> 3;               // 0..63
  const int b = (flat & 7) + 8 * (i0 & 3);
  const int dg = i0 >> 2;                 // 0..15 -> d base dg*32

  const int w = t >> 6;                   // wave 0..3
  const int dh = w & 1;                   // 16-d half
  const int kh = w >> 1;                  // 32-k half
  const int lane = t & 63;
  const int q = lane >> 4;
  const int m = lane & 15;

  // a-staging lane constants (R15-verified): 8 chunks/row of 16B
  const int rs = lane >> 3;               // row-sub 0..7
  const int csw_a = (lane & 7) ^ (rs & 7);
  // x-staging: 16 chunks/row of 16B; instr covers 4 rows (lane>>4)
  const int rx = lane >> 4;               // 0..3

  const float* xdg = x + ((size_t)b * Dv + dg * 32) * Nv;
  const unsigned short* abase = assign + (size_t)b * 16 * (Kv * 64);

#define STAGE(buf, rr)                                                        \
  {                                                                           \
    _Pragma("unroll")                                                         \
    for (int s = 0; s < 2; s++) {                                             \
      int tile = (rr) * 2 + s;                                                \
      _Pragma("unroll")                                                       \
      for (int i = 0; i < 2; i++) {                                           \
        int dl = w * 8 + i * 4 + rx;      /* local d row 0..31 */             \
        const float* _xs = xdg + (size_t)dl * Nv + tile * 64                  \
                           + (((lane & 15) ^ (dl & 7)) * 4);                  \
        GLOAD_LDS16(_xs, &xsf[buf][s][(w * 8 + i * 4) * 64]);                 \
      }                                                                       \
      const unsigned short* _a1 = abase + (size_t)tile * (Kv * 64)            \
                                  + (w * 16 + rs) * 64 + csw_a * 8;           \
      GLOAD_LDS16(_a1, &as_[buf][s][w * 1024]);                               \
      GLOAD_LDS16(_a1 + 512, &as_[buf][s][w * 1024 + 512]);                   \
    }                                                                         \
  }

  f32x4 acc0 = {0.f,0.f,0.f,0.f}, acc1 = {0.f,0.f,0.f,0.f};

  STAGE(0, 0)
  asm volatile("s_waitcnt vmcnt(0)");
  __syncthreads();

  int buf = 0;
  const int row = dh * 16 + m;            // x LDS row
  const int mk7 = m & 7;
#pragma unroll
  for (int rr = 0; rr < 8; rr++) {
    if (rr < 7) STAGE(buf ^ 1, rr + 1)
#pragma unroll
    for (int s = 0; s < 2; s++) {
#pragma unroll
      for (int nc = 0; nc < 2; nc++) {
        const int c0 = nc * 8 + q * 2;
        float4 f0 = *(const float4*)&xsf[buf][s][row * 64 + ((c0 ^ mk7)) * 4];
        float4 f1 = *(const float4*)&xsf[buf][s][row * 64 + (((c0 + 1) ^ mk7)) * 4];
        bf16x8 xv;
        unsigned* xu = (unsigned*)&xv;
        xu[0] = cvtpk(f0.x, f0.y);
        xu[1] = cvtpk(f0.z, f0.w);
        xu[2] = cvtpk(f1.x, f1.y);
        xu[3] = cvtpk(f1.z, f1.w);
        const int cidx = ((nc * 4 + q) ^ mk7) * 8;
        bf16x8 a0 = *(const bf16x8*)&as_[buf][s][(kh * 32 + m) * 64 + cidx];
        bf16x8 a1 = *(const bf16x8*)&as_[buf][s][(kh * 32 + 16 + m) * 64 + cidx];
        acc0 = __builtin_amdgcn_mfma_f32_16x16x32_bf16(xv, a0, acc0, 0, 0, 0);
        acc1 = __builtin_amdgcn_mfma_f32_16x16x32_bf16(xv, a1, acc1, 0, 0, 0);
      }
    }
    asm volatile("s_waitcnt vmcnt(0)");
    __syncthreads();
    buf ^= 1;
  }
#undef STAGE

  // epilogue: d = dg*32 + dh*16 + q*4 + r; k = kh*32 + {0,16} + m
  const int k0 = kh * 32 + m;
  const int k1 = k0 + 16;
  const float as0 = asum[b * Kv + k0];
  const float as1 = asum[b * Kv + k1];
  float ss0 = 0.f, ss1 = 0.f;
#pragma unroll
  for (int r = 0; r < 4; r++) {
    int d = dg * 32 + dh * 16 + q * 4 + r;
    float v0 = acc0[r] - centers[d * Kv + k0] * as0;
    float v1 = acc1[r] - centers[d * Kv + k1] * as1;
    vlad[((size_t)b * Dv + d) * Kv + k0] = v0;
    vlad[((size_t)b * Dv + d) * Kv + k1] = v1;
    ss0 = fmaf(v0, v0, ss0);
    ss1 = fmaf(v1, v1, ss1);
  }
  ss0 += __shfl_xor(ss0, 16); ss0 += __shfl_xor(ss0, 32);
  ss1 += __shfl_xor(ss1, 16); ss1 += __shfl_xor(ss1, 32);
  if (q == 0) {
    atomicAdd(&colsq[b * Kv + k0], ss0);
    atomicAdd(&colsq[b * Kv + k1], ss1);
  }
}

// ---------------------------------------------------------------------------
// Kernel D: out = vlad * colscale[b,k] * bscale[b]; float4-vectorized.
// ---------------------------------------------------------------------------
__global__ __launch_bounds__(256) void scale_kernel(
    const float* __restrict__ vlad, const float* __restrict__ colsq,
    float* __restrict__ out) {
  const int t = threadIdx.x;
  const size_t i = ((size_t)blockIdx.x * 256 + t) * 4;
  const int b = (int)(i >> 15);
  __shared__ float scs[64];
  __shared__ float bsh;
  if (t < 64) {
    float tot = colsq[b * Kv + t];
    float sc = 1.0f / fmaxf(sqrtf(tot), EPSv);
    scs[t] = sc;
    float contrib = tot * sc * sc;
#pragma unroll
    for (int off = 32; off > 0; off >>= 1) contrib += __shfl_down(contrib, off);
    if (t == 0) bsh = 1.0f / fmaxf(sqrtf(contrib), EPSv);
  }
  __syncthreads();
  float4 v = *(const float4*)&vlad[i];
  const int k = (int)(i & 63);
  float4 o;
  o.x = v.x * scs[k + 0] * bsh;
  o.y = v.y * scs[k + 1] * bsh;
  o.z = v.z * scs[k + 2] * bsh;
  o.w = v.w * scs[k + 3] * bsh;
  *(float4*)&out[i] = o;
}

extern "C" void kernel_launch(void* const* d_in, const int* in_sizes, int n_in,
                              void* d_out, int out_size, void* d_ws, size_t ws_size,
                              hipStream_t stream) {
  const float* x = (const float*)d_in[0];        // [B, D, N]
  const float* w = (const float*)d_in[1];        // [K, D]
  const float* centers = (const float*)d_in[2];  // [D, K]
  float* out = (float*)d_out;                    // [B, D*K]

  char* ws = (char*)d_ws;
  unsigned short* assign = (unsigned short*)ws;               // tiled, 4 MB
  float* vlad = (float*)(ws + 4194304);                       // [B][D][K] fp32, 4 MB
  unsigned short* wbf = (unsigned short*)(ws + 8388608);      // [K][D] bf16, 64 KB
  float* asum = (float*)(ws + 8454144);                       // B*K
  float* colsq = asum + Bv * Kv;                              // B*K

  wconv<<<32, 256, 0, stream>>>(w, wbf, asum);   // also zeros asum+colsq
  fused_scores<<<512, 512, 0, stream>>>(x, wbf, assign, asum);
  vlad_stage<<<512, 256, 0, stream>>>(x, assign, centers, asum, vlad, colsq);
  scale_kernel<<<1024, 256, 0, stream>>>(vlad, colsq, out);
}

// Round 12
// 122.675 us; speedup vs baseline: 1.2391x; 1.0077x over previous
//
#include <hip/hip_runtime.h>
#include <hip/hip_bf16.h>

#define Bv 32
#define Dv 512
#define Kv 64
#define Nv 1024
#define EPSv 1e-12f

typedef __attribute__((ext_vector_type(8))) short bf16x8;
typedef __attribute__((ext_vector_type(4))) float f32x4;

// fp32 -> bf16 (RNE), bit-level
__device__ __forceinline__ unsigned short f2b(float f) {
  union { float f; unsigned u; } v; v.f = f;
  unsigned r = v.u + 0x7fffu + ((v.u >> 16) & 1u);
  return (unsigned short)(r >> 16);
}
__device__ __forceinline__ unsigned pack2(float a, float b) {
  return (unsigned)f2b(a) | ((unsigned)f2b(b) << 16);
}
// HW packed cvt, RNE — same rounding as f2b/pack2. lo = a, hi = b.
__device__ __forceinline__ unsigned cvtpk(float a, float b) {
  unsigned r;
  asm("v_cvt_pk_bf16_f32 %0, %1, %2" : "=v"(r) : "v"(a), "v"(b));
  return r;
}

// global -> LDS direct copy, 16B per lane, no dest VGPRs (deep MLP).
#define GLOAD_LDS16(gsrc, ldst)                                             \
  __builtin_amdgcn_global_load_lds(                                         \
      (const __attribute__((address_space(1))) void*)(gsrc),                \
      (__attribute__((address_space(3))) void*)(ldst), 16, 0, 0)

// ---------------------------------------------------------------------------
// Kernel W: convert conv_w (K x D fp32) -> bf16, AND zero asum+colsq.
// ---------------------------------------------------------------------------
__global__ __launch_bounds__(256) void wconv(const float* __restrict__ w,
                                             unsigned short* __restrict__ wbf,
                                             float* __restrict__ zbuf) {
  int id = blockIdx.x * 256 + threadIdx.x;
  int i = id * 4;
  float4 v = *(const float4*)&w[i];
  uint2 o = make_uint2(pack2(v.x, v.y), pack2(v.z, v.w));
  *(uint2*)&wbf[i] = o;
  if (id < 2 * Bv * Kv) zbuf[id] = 0.f;   // asum (B*K) + colsq (B*K)
}

// ---------------------------------------------------------------------------
// Kernel 1 (fused T+A) — byte-identical to R16 (verified 123.6 total).
// ---------------------------------------------------------------------------
__global__ __launch_bounds__(512) void fused_scores(
    const float* __restrict__ x, const unsigned short* __restrict__ wbf,
    unsigned short* __restrict__ assign, float* __restrict__ asum) {
  __shared__ unsigned short xT[64 * 520];   // [n][d], pitch 520 shorts
  __shared__ float redmax[4][64];
  __shared__ float redsum[4][64];

  const int t = threadIdx.x;   // 0..511
  const int flat = blockIdx.x;            // 0..511
  const int i0 = flat >> 3;               // 0..63
  const int b = (flat & 7) + 8 * (i0 & 3);
  const int nt = i0 >> 2;                 // 0..15
  const int n0 = nt * 64;

  // ---------------- staging ----------------
  {
    const int lo = t & 15;
    const int hi = t >> 4;
    const int s = (lo >> 1) & 3;
    const float* xb = x + (size_t)b * Dv * Nv + n0;
#pragma unroll
    for (int r = 0; r < 8; r++) {
      int d = (hi + 32 * r) * 2;
      int n4 = lo * 4;
      float4 v0 = *(const float4*)&xb[(size_t)d * Nv + n4];
      float4 v1 = *(const float4*)&xb[(size_t)(d + 1) * Nv + n4];
      unsigned w0 = pack2(v0.x, v1.x);
      unsigned w1 = pack2(v0.y, v1.y);
      unsigned w2 = pack2(v0.z, v1.z);
      unsigned w3 = pack2(v0.w, v1.w);
      unsigned a0 = (s & 1) ? w1 : w0, a1 = (s & 1) ? w2 : w1,
               a2 = (s & 1) ? w3 : w2, a3 = (s & 1) ? w0 : w3;
      unsigned b0 = (s & 2) ? a2 : a0, b1 = (s & 2) ? a3 : a1,
               b2 = (s & 2) ? a0 : a2, b3 = (s & 2) ? a1 : a3;
      *(unsigned*)&xT[(n4 + ((0 + s) & 3)) * 520 + d] = b0;
      *(unsigned*)&xT[(n4 + ((1 + s) & 3)) * 520 + d] = b1;
      *(unsigned*)&xT[(n4 + ((2 + s) & 3)) * 520 + d] = b2;
      *(unsigned*)&xT[(n4 + ((3 + s) & 3)) * 520 + d] = b3;
    }
  }
  __syncthreads();

  // ---------------- scores GEMM ----------------
  const int wv = t >> 6;
  const int lane = t & 63;
  const int q = lane >> 4;
  const int m = lane & 15;
  const int k16 = wv & 3;
  const int nsub = wv >> 2;

  f32x4 acc0 = {0.f, 0.f, 0.f, 0.f};
  f32x4 acc1 = {0.f, 0.f, 0.f, 0.f};

  const unsigned short* wp = wbf + (size_t)(k16 * 16 + m) * Dv + q * 8;
  const unsigned short* l0 = &xT[(nsub * 32 + m) * 520 + q * 8];
  const unsigned short* l1 = l0 + 16 * 520;

#pragma unroll
  for (int d0 = 0; d0 < Dv; d0 += 32) {
    bf16x8 af = *(const bf16x8*)(wp + d0);
    bf16x8 bf0 = *(const bf16x8*)(l0 + d0);
    bf16x8 bf1 = *(const bf16x8*)(l1 + d0);
    acc0 = __builtin_amdgcn_mfma_f32_16x16x32_bf16(af, bf0, acc0, 0, 0, 0);
    acc1 = __builtin_amdgcn_mfma_f32_16x16x32_bf16(af, bf1, acc1, 0, 0, 0);
  }

  // ---------------- softmax over k (64) ----------------
  float m0 = fmaxf(fmaxf(acc0[0], acc0[1]), fmaxf(acc0[2], acc0[3]));
  float m1 = fmaxf(fmaxf(acc1[0], acc1[1]), fmaxf(acc1[2], acc1[3]));
  m0 = fmaxf(m0, __shfl_xor(m0, 16)); m0 = fmaxf(m0, __shfl_xor(m0, 32));
  m1 = fmaxf(m1, __shfl_xor(m1, 16)); m1 = fmaxf(m1, __shfl_xor(m1, 32));
  if (q == 0) {
    redmax[k16][nsub * 32 + m] = m0;
    redmax[k16][nsub * 32 + 16 + m] = m1;
  }
  __syncthreads();
  const int c0 = nsub * 32 + m, c1 = c0 + 16;
  float mc0 = fmaxf(fmaxf(redmax[0][c0], redmax[1][c0]), fmaxf(redmax[2][c0], redmax[3][c0]));
  float mc1 = fmaxf(fmaxf(redmax[0][c1], redmax[1][c1]), fmaxf(redmax[2][c1], redmax[3][c1]));

  float e0[4], e1[4];
  float s0 = 0.f, s1 = 0.f;
#pragma unroll
  for (int r = 0; r < 4; r++) {
    e0[r] = __expf(acc0[r] - mc0); s0 += e0[r];
    e1[r] = __expf(acc1[r] - mc1); s1 += e1[r];
  }
  s0 += __shfl_xor(s0, 16); s0 += __shfl_xor(s0, 32);
  s1 += __shfl_xor(s1, 16); s1 += __shfl_xor(s1, 32);
  if (q == 0) {
    redsum[k16][c0] = s0;
    redsum[k16][c1] = s1;
  }
  __syncthreads();
  float sc0 = 1.0f / (redsum[0][c0] + redsum[1][c0] + redsum[2][c0] + redsum[3][c0]);
  float sc1 = 1.0f / (redsum[0][c1] + redsum[1][c1] + redsum[2][c1] + redsum[3][c1]);

  unsigned short* at_ = assign + ((size_t)b * 16 + nt) * (Kv * 64)
                        + (size_t)(k16 * 16 + q * 4) * 64 + nsub * 32;
#pragma unroll
  for (int r = 0; r < 4; r++) {
    float v0 = e0[r] * sc0;
    float v1 = e1[r] * sc1;
    at_[r * 64 + m] = f2b(v0);
    at_[r * 64 + 16 + m] = f2b(v1);
    float p = v0 + v1;
    p += __shfl_xor(p, 1); p += __shfl_xor(p, 2);
    p += __shfl_xor(p, 4); p += __shfl_xor(p, 8);
    if (m == 0) atomicAdd(&asum[b * Kv + k16 * 16 + q * 4 + r], p);
  }
}

// ---------------------------------------------------------------------------
// Kernel 2 (R17): R16's LDS-staged fp32-x GEMM with T4 COUNTED-vmcnt
// pipeline. R16 drained vmcnt(0) each round — waiting for the freshly
// issued next-tile loads and defeating the double buffer. Now:
//   prologue: STAGE pair0, pair1 (16 loads out); vmcnt(8) -> pair0 ready
//   round rr: compute buf=rr&1; raw s_barrier; STAGE(buf, rr+2) [8 loads];
//             vmcnt(8) = wait ONLY the older 8 (pair rr+1, issued a full
//             round ago); raw s_barrier.
// __syncthreads() replaced by __builtin_amdgcn_s_barrier() (HIP's
// __syncthreads forces a vmcnt(0) drain); sched_barrier(0) fences per
// rule #18. Staging/compute/swizzle bodies byte-identical to R16.
// ---------------------------------------------------------------------------
__global__ __launch_bounds__(256) void vlad_stage(
    const float* __restrict__ x, const unsigned short* __restrict__ assign,
    const float* __restrict__ centers, const float* __restrict__ asum,
    float* __restrict__ vlad, float* __restrict__ colsq) {
  __shared__ float xsf[2][2][2048];            // [buf][tile][32d x 64n] 8KB
  __shared__ unsigned short as_[2][2][4096];   // [buf][tile][64k x 64n] 8KB

  const int t = threadIdx.x;
  const int flat = blockIdx.x;            // 0..511
  const int i0 = flat >> 3;               // 0..63
  const int b = (flat & 7) + 8 * (i0 & 3);
  const int dg = i0 >> 2;                 // 0..15 -> d base dg*32

  const int w = t >> 6;                   // wave 0..3
  const int dh = w & 1;                   // 16-d half
  const int kh = w >> 1;                  // 32-k half
  const int lane = t & 63;
  const int q = lane >> 4;
  const int m = lane & 15;

  const int rs = lane >> 3;               // row-sub 0..7
  const int csw_a = (lane & 7) ^ (rs & 7);
  const int rx = lane >> 4;               // 0..3

  const float* xdg = x + ((size_t)b * Dv + dg * 32) * Nv;
  const unsigned short* abase = assign + (size_t)b * 16 * (Kv * 64);

  // 8 gload_lds per thread per STAGE (4 x-slab + 4 a-slab)
#define STAGE(buf, rr)                                                        \
  {                                                                           \
    _Pragma("unroll")                                                         \
    for (int s = 0; s < 2; s++) {                                             \
      int tile = (rr) * 2 + s;                                                \
      _Pragma("unroll")                                                       \
      for (int i = 0; i < 2; i++) {                                           \
        int dl = w * 8 + i * 4 + rx;      /* local d row 0..31 */             \
        const float* _xs = xdg + (size_t)dl * Nv + tile * 64                  \
                           + (((lane & 15) ^ (dl & 7)) * 4);                  \
        GLOAD_LDS16(_xs, &xsf[buf][s][(w * 8 + i * 4) * 64]);                 \
      }                                                                       \
      const unsigned short* _a1 = abase + (size_t)tile * (Kv * 64)            \
                                  + (w * 16 + rs) * 64 + csw_a * 8;           \
      GLOAD_LDS16(_a1, &as_[buf][s][w * 1024]);                               \
      GLOAD_LDS16(_a1 + 512, &as_[buf][s][w * 1024 + 512]);                   \
    }                                                                         \
  }

  f32x4 acc0 = {0.f,0.f,0.f,0.f}, acc1 = {0.f,0.f,0.f,0.f};

  STAGE(0, 0)
  STAGE(1, 1)
  asm volatile("s_waitcnt vmcnt(8)");     // pair0's 8 done (8 younger remain)
  __builtin_amdgcn_sched_barrier(0);
  __builtin_amdgcn_s_barrier();
  __builtin_amdgcn_sched_barrier(0);

  const int row = dh * 16 + m;            // x LDS row
  const int mk7 = m & 7;
#pragma unroll
  for (int rr = 0; rr < 8; rr++) {
    const int buf = rr & 1;
#pragma unroll
    for (int s = 0; s < 2; s++) {
#pragma unroll
      for (int nc = 0; nc < 2; nc++) {
        const int c0 = nc * 8 + q * 2;
        float4 f0 = *(const float4*)&xsf[buf][s][row * 64 + ((c0 ^ mk7)) * 4];
        float4 f1 = *(const float4*)&xsf[buf][s][row * 64 + (((c0 + 1) ^ mk7)) * 4];
        bf16x8 xv;
        unsigned* xu = (unsigned*)&xv;
        xu[0] = cvtpk(f0.x, f0.y);
        xu[1] = cvtpk(f0.z, f0.w);
        xu[2] = cvtpk(f1.x, f1.y);
        xu[3] = cvtpk(f1.z, f1.w);
        const int cidx = ((nc * 4 + q) ^ mk7) * 8;
        bf16x8 a0 = *(const bf16x8*)&as_[buf][s][(kh * 32 + m) * 64 + cidx];
        bf16x8 a1 = *(const bf16x8*)&as_[buf][s][(kh * 32 + 16 + m) * 64 + cidx];
        acc0 = __builtin_amdgcn_mfma_f32_16x16x32_bf16(xv, a0, acc0, 0, 0, 0);
        acc1 = __builtin_amdgcn_mfma_f32_16x16x32_bf16(xv, a1, acc1, 0, 0, 0);
      }
    }
    if (rr < 7) {
      __builtin_amdgcn_sched_barrier(0);
      __builtin_amdgcn_s_barrier();       // all waves done reading buf
      __builtin_amdgcn_sched_barrier(0);
      if (rr < 6) {
        STAGE(buf, rr + 2)                // refill buf with pair rr+2
        asm volatile("s_waitcnt vmcnt(8)");  // older 8 (pair rr+1) done
      } else {
        asm volatile("s_waitcnt vmcnt(0)");  // last pair (7) done
      }
      __builtin_amdgcn_sched_barrier(0);
      __builtin_amdgcn_s_barrier();       // pair rr+1 visible to all
      __builtin_amdgcn_sched_barrier(0);
    }
  }
#undef STAGE

  // epilogue: d = dg*32 + dh*16 + q*4 + r; k = kh*32 + {0,16} + m
  const int k0 = kh * 32 + m;
  const int k1 = k0 + 16;
  const float as0 = asum[b * Kv + k0];
  const float as1 = asum[b * Kv + k1];
  float ss0 = 0.f, ss1 = 0.f;
#pragma unroll
  for (int r = 0; r < 4; r++) {
    int d = dg * 32 + dh * 16 + q * 4 + r;
    float v0 = acc0[r] - centers[d * Kv + k0] * as0;
    float v1 = acc1[r] - centers[d * Kv + k1] * as1;
    vlad[((size_t)b * Dv + d) * Kv + k0] = v0;
    vlad[((size_t)b * Dv + d) * Kv + k1] = v1;
    ss0 = fmaf(v0, v0, ss0);
    ss1 = fmaf(v1, v1, ss1);
  }
  ss0 += __shfl_xor(ss0, 16); ss0 += __shfl_xor(ss0, 32);
  ss1 += __shfl_xor(ss1, 16); ss1 += __shfl_xor(ss1, 32);
  if (q == 0) {
    atomicAdd(&colsq[b * Kv + k0], ss0);
    atomicAdd(&colsq[b * Kv + k1], ss1);
  }
}

// ---------------------------------------------------------------------------
// Kernel D: out = vlad * colscale[b,k] * bscale[b]; float4-vectorized.
// ---------------------------------------------------------------------------
__global__ __launch_bounds__(256) void scale_kernel(
    const float* __restrict__ vlad, const float* __restrict__ colsq,
    float* __restrict__ out) {
  const int t = threadIdx.x;
  const size_t i = ((size_t)blockIdx.x * 256 + t) * 4;
  const int b = (int)(i >> 15);
  __shared__ float scs[64];
  __shared__ float bsh;
  if (t < 64) {
    float tot = colsq[b * Kv + t];
    float sc = 1.0f / fmaxf(sqrtf(tot), EPSv);
    scs[t] = sc;
    float contrib = tot * sc * sc;
#pragma unroll
    for (int off = 32; off > 0; off >>= 1) contrib += __shfl_down(contrib, off);
    if (t == 0) bsh = 1.0f / fmaxf(sqrtf(contrib), EPSv);
  }
  __syncthreads();
  float4 v = *(const float4*)&vlad[i];
  const int k = (int)(i & 63);
  float4 o;
  o.x = v.x * scs[k + 0] * bsh;
  o.y = v.y * scs[k + 1] * bsh;
  o.z = v.z * scs[k + 2] * bsh;
  o.w = v.w * scs[k + 3] * bsh;
  *(float4*)&out[i] = o;
}

extern "C" void kernel_launch(void* const* d_in, const int* in_sizes, int n_in,
                              void* d_out, int out_size, void* d_ws, size_t ws_size,
                              hipStream_t stream) {
  const float* x = (const float*)d_in[0];        // [B, D, N]
  const float* w = (const float*)d_in[1];        // [K, D]
  const float* centers = (const float*)d_in[2];  // [D, K]
  float* out = (float*)d_out;                    // [B, D*K]

  char* ws = (char*)d_ws;
  unsigned short* assign = (unsigned short*)ws;               // tiled, 4 MB
  float* vlad = (float*)(ws + 4194304);                       // [B][D][K] fp32, 4 MB
  unsigned short* wbf = (unsigned short*)(ws + 8388608);      // [K][D] bf16, 64 KB
  float* asum = (float*)(ws + 8454144);                       // B*K
  float* colsq = asum + Bv * Kv;                              // B*K

  wconv<<<32, 256, 0, stream>>>(w, wbf, asum);   // also zeros asum+colsq
  fused_scores<<<512, 512, 0, stream>>>(x, wbf, assign, asum);
  vlad_stage<<<512, 256, 0, stream>>>(x, assign, centers, asum, vlad, colsq);
  scale_kernel<<<1024, 256, 0, stream>>>(vlad, colsq, out);
}

// Round 13
// 122.357 us; speedup vs baseline: 1.2423x; 1.0026x over previous
//
#include <hip/hip_runtime.h>
#include <hip/hip_bf16.h>

#define Bv 32
#define Dv 512
#define Kv 64
#define Nv 1024
#define EPSv 1e-12f

typedef __attribute__((ext_vector_type(8))) short bf16x8;
typedef __attribute__((ext_vector_type(4))) float f32x4;

// fp32 -> bf16 (RNE), bit-level
__device__ __forceinline__ unsigned short f2b(float f) {
  union { float f; unsigned u; } v; v.f = f;
  unsigned r = v.u + 0x7fffu + ((v.u >> 16) & 1u);
  return (unsigned short)(r >> 16);
}
__device__ __forceinline__ unsigned pack2(float a, float b) {
  return (unsigned)f2b(a) | ((unsigned)f2b(b) << 16);
}
// HW packed cvt, RNE — same rounding as f2b/pack2. lo = a, hi = b.
__device__ __forceinline__ unsigned cvtpk(float a, float b) {
  unsigned r;
  asm("v_cvt_pk_bf16_f32 %0, %1, %2" : "=v"(r) : "v"(a), "v"(b));
  return r;
}

// global -> LDS direct copy, 16B per lane, no dest VGPRs (deep MLP).
#define GLOAD_LDS16(gsrc, ldst)                                             \
  __builtin_amdgcn_global_load_lds(                                         \
      (const __attribute__((address_space(1))) void*)(gsrc),                \
      (__attribute__((address_space(3))) void*)(ldst), 16, 0, 0)

// ---------------------------------------------------------------------------
// Kernel W: convert conv_w (K x D fp32) -> bf16, AND zero asum+colsq.
// ---------------------------------------------------------------------------
__global__ __launch_bounds__(256) void wconv(const float* __restrict__ w,
                                             unsigned short* __restrict__ wbf,
                                             float* __restrict__ zbuf) {
  int id = blockIdx.x * 256 + threadIdx.x;
  int i = id * 4;
  float4 v = *(const float4*)&w[i];
  uint2 o = make_uint2(pack2(v.x, v.y), pack2(v.z, v.w));
  *(uint2*)&wbf[i] = o;
  if (id < 2 * Bv * Kv) zbuf[id] = 0.f;   // asum (B*K) + colsq (B*K)
}

// ---------------------------------------------------------------------------
// Kernel 1 (fused T+A), R18: staging converted to an asm-pinned DEPTH-8
// load ring with counted vmcnt (T4, compiler-proof per R13 mechanism).
// Old schedule kept only ~2 load-pairs in flight (pack chained on load);
// now: prologue issues pairs 0..3; round r waits vmcnt(6/4/2/0) for ONLY
// its pair, packs+writes LDS, reissues pair r+4. Ring = 32 VGPR, stays
// <128 -> 2 blk/CU x 8 waves kept. Pack/rotate/GEMM/softmax bodies
// byte-identical to R17 (verified 122.68).
// ---------------------------------------------------------------------------
__global__ __launch_bounds__(512) void fused_scores(
    const float* __restrict__ x, const unsigned short* __restrict__ wbf,
    unsigned short* __restrict__ assign, float* __restrict__ asum) {
  __shared__ unsigned short xT[64 * 520];   // [n][d], pitch 520 shorts
  __shared__ float redmax[4][64];
  __shared__ float redsum[4][64];

  const int t = threadIdx.x;   // 0..511
  const int flat = blockIdx.x;            // 0..511
  const int i0 = flat >> 3;               // 0..63
  const int b = (flat & 7) + 8 * (i0 & 3);
  const int nt = i0 >> 2;                 // 0..15
  const int n0 = nt * 64;

  // ---------------- staging (asm depth-8 ring) ----------------
  {
    const int lo = t & 15;
    const int hi = t >> 4;
    const int s = (lo >> 1) & 3;
    const float* xb = x + (size_t)b * Dv * Nv + n0 + lo * 4;
    float4 xr0[4], xr1[4];

#define FS_ISSUE(slot, r)                                                     \
  {                                                                           \
    const float* _s = xb + (size_t)((hi + 32 * (r)) * 2) * Nv;                \
    asm volatile("global_load_dwordx4 %0, %1, off"                            \
                 : "=v"(xr0[slot]) : "v"(_s));                                \
    asm volatile("global_load_dwordx4 %0, %1, off"                            \
                 : "=v"(xr1[slot]) : "v"(_s + Nv));                           \
  }

    FS_ISSUE(0, 0) FS_ISSUE(1, 1) FS_ISSUE(2, 2) FS_ISSUE(3, 3)
    __builtin_amdgcn_sched_barrier(0);

#pragma unroll
    for (int r = 0; r < 8; r++) {
      const int nout = (r < 5) ? 6 : (14 - 2 * r);   // 6,6,6,6,6,4,2,0
      asm volatile("s_waitcnt vmcnt(%0)" :: "i"(nout));
      __builtin_amdgcn_sched_barrier(0);
      float4 v0 = xr0[r & 3];
      float4 v1 = xr1[r & 3];
      int d = (hi + 32 * r) * 2;
      int n4 = lo * 4;
      unsigned w0 = pack2(v0.x, v1.x);
      unsigned w1 = pack2(v0.y, v1.y);
      unsigned w2 = pack2(v0.z, v1.z);
      unsigned w3 = pack2(v0.w, v1.w);
      unsigned a0 = (s & 1) ? w1 : w0, a1 = (s & 1) ? w2 : w1,
               a2 = (s & 1) ? w3 : w2, a3 = (s & 1) ? w0 : w3;
      unsigned b0 = (s & 2) ? a2 : a0, b1 = (s & 2) ? a3 : a1,
               b2 = (s & 2) ? a0 : a2, b3 = (s & 2) ? a1 : a3;
      *(unsigned*)&xT[(n4 + ((0 + s) & 3)) * 520 + d] = b0;
      *(unsigned*)&xT[(n4 + ((1 + s) & 3)) * 520 + d] = b1;
      *(unsigned*)&xT[(n4 + ((2 + s) & 3)) * 520 + d] = b2;
      *(unsigned*)&xT[(n4 + ((3 + s) & 3)) * 520 + d] = b3;
      if (r < 4) FS_ISSUE(r & 3, r + 4)
      __builtin_amdgcn_sched_barrier(0);
    }
#undef FS_ISSUE
  }
  __syncthreads();

  // ---------------- scores GEMM ----------------
  const int wv = t >> 6;
  const int lane = t & 63;
  const int q = lane >> 4;
  const int m = lane & 15;
  const int k16 = wv & 3;
  const int nsub = wv >> 2;

  f32x4 acc0 = {0.f, 0.f, 0.f, 0.f};
  f32x4 acc1 = {0.f, 0.f, 0.f, 0.f};

  const unsigned short* wp = wbf + (size_t)(k16 * 16 + m) * Dv + q * 8;
  const unsigned short* l0 = &xT[(nsub * 32 + m) * 520 + q * 8];
  const unsigned short* l1 = l0 + 16 * 520;

#pragma unroll
  for (int d0 = 0; d0 < Dv; d0 += 32) {
    bf16x8 af = *(const bf16x8*)(wp + d0);
    bf16x8 bf0 = *(const bf16x8*)(l0 + d0);
    bf16x8 bf1 = *(const bf16x8*)(l1 + d0);
    acc0 = __builtin_amdgcn_mfma_f32_16x16x32_bf16(af, bf0, acc0, 0, 0, 0);
    acc1 = __builtin_amdgcn_mfma_f32_16x16x32_bf16(af, bf1, acc1, 0, 0, 0);
  }

  // ---------------- softmax over k (64) ----------------
  float m0 = fmaxf(fmaxf(acc0[0], acc0[1]), fmaxf(acc0[2], acc0[3]));
  float m1 = fmaxf(fmaxf(acc1[0], acc1[1]), fmaxf(acc1[2], acc1[3]));
  m0 = fmaxf(m0, __shfl_xor(m0, 16)); m0 = fmaxf(m0, __shfl_xor(m0, 32));
  m1 = fmaxf(m1, __shfl_xor(m1, 16)); m1 = fmaxf(m1, __shfl_xor(m1, 32));
  if (q == 0) {
    redmax[k16][nsub * 32 + m] = m0;
    redmax[k16][nsub * 32 + 16 + m] = m1;
  }
  __syncthreads();
  const int c0 = nsub * 32 + m, c1 = c0 + 16;
  float mc0 = fmaxf(fmaxf(redmax[0][c0], redmax[1][c0]), fmaxf(redmax[2][c0], redmax[3][c0]));
  float mc1 = fmaxf(fmaxf(redmax[0][c1], redmax[1][c1]), fmaxf(redmax[2][c1], redmax[3][c1]));

  float e0[4], e1[4];
  float s0 = 0.f, s1 = 0.f;
#pragma unroll
  for (int r = 0; r < 4; r++) {
    e0[r] = __expf(acc0[r] - mc0); s0 += e0[r];
    e1[r] = __expf(acc1[r] - mc1); s1 += e1[r];
  }
  s0 += __shfl_xor(s0, 16); s0 += __shfl_xor(s0, 32);
  s1 += __shfl_xor(s1, 16); s1 += __shfl_xor(s1, 32);
  if (q == 0) {
    redsum[k16][c0] = s0;
    redsum[k16][c1] = s1;
  }
  __syncthreads();
  float sc0 = 1.0f / (redsum[0][c0] + redsum[1][c0] + redsum[2][c0] + redsum[3][c0]);
  float sc1 = 1.0f / (redsum[0][c1] + redsum[1][c1] + redsum[2][c1] + redsum[3][c1]);

  unsigned short* at_ = assign + ((size_t)b * 16 + nt) * (Kv * 64)
                        + (size_t)(k16 * 16 + q * 4) * 64 + nsub * 32;
#pragma unroll
  for (int r = 0; r < 4; r++) {
    float v0 = e0[r] * sc0;
    float v1 = e1[r] * sc1;
    at_[r * 64 + m] = f2b(v0);
    at_[r * 64 + 16 + m] = f2b(v1);
    float p = v0 + v1;
    p += __shfl_xor(p, 1); p += __shfl_xor(p, 2);
    p += __shfl_xor(p, 4); p += __shfl_xor(p, 8);
    if (m == 0) atomicAdd(&asum[b * Kv + k16 * 16 + q * 4 + r], p);
  }
}

// ---------------------------------------------------------------------------
// Kernel 2 — byte-identical to R17 (verified): LDS-staged fp32-x GEMM,
// counted-vmcnt double buffer, raw barriers, both-sides XOR swizzle.
// ---------------------------------------------------------------------------
__global__ __launch_bounds__(256) void vlad_stage(
    const float* __restrict__ x, const unsigned short* __restrict__ assign,
    const float* __restrict__ centers, const float* __restrict__ asum,
    float* __restrict__ vlad, float* __restrict__ colsq) {
  __shared__ float xsf[2][2][2048];            // [buf][tile][32d x 64n] 8KB
  __shared__ unsigned short as_[2][2][4096];   // [buf][tile][64k x 64n] 8KB

  const int t = threadIdx.x;
  const int flat = blockIdx.x;            // 0..511
  const int i0 = flat >> 3;               // 0..63
  const int b = (flat & 7) + 8 * (i0 & 3);
  const int dg = i0 >> 2;                 // 0..15 -> d base dg*32

  const int w = t >> 6;                   // wave 0..3
  const int dh = w & 1;                   // 16-d half
  const int kh = w >> 1;                  // 32-k half
  const int lane = t & 63;
  const int q = lane >> 4;
  const int m = lane & 15;

  const int rs = lane >> 3;               // row-sub 0..7
  const int csw_a = (lane & 7) ^ (rs & 7);
  const int rx = lane >> 4;               // 0..3

  const float* xdg = x + ((size_t)b * Dv + dg * 32) * Nv;
  const unsigned short* abase = assign + (size_t)b * 16 * (Kv * 64);

  // 8 gload_lds per thread per STAGE (4 x-slab + 4 a-slab)
#define STAGE(buf, rr)                                                        \
  {                                                                           \
    _Pragma("unroll")                                                         \
    for (int s = 0; s < 2; s++) {                                             \
      int tile = (rr) * 2 + s;                                                \
      _Pragma("unroll")                                                       \
      for (int i = 0; i < 2; i++) {                                           \
        int dl = w * 8 + i * 4 + rx;      /* local d row 0..31 */             \
        const float* _xs = xdg + (size_t)dl * Nv + tile * 64                  \
                           + (((lane & 15) ^ (dl & 7)) * 4);                  \
        GLOAD_LDS16(_xs, &xsf[buf][s][(w * 8 + i * 4) * 64]);                 \
      }                                                                       \
      const unsigned short* _a1 = abase + (size_t)tile * (Kv * 64)            \
                                  + (w * 16 + rs) * 64 + csw_a * 8;           \
      GLOAD_LDS16(_a1, &as_[buf][s][w * 1024]);                               \
      GLOAD_LDS16(_a1 + 512, &as_[buf][s][w * 1024 + 512]);                   \
    }                                                                         \
  }

  f32x4 acc0 = {0.f,0.f,0.f,0.f}, acc1 = {0.f,0.f,0.f,0.f};

  STAGE(0, 0)
  STAGE(1, 1)
  asm volatile("s_waitcnt vmcnt(8)");     // pair0's 8 done (8 younger remain)
  __builtin_amdgcn_sched_barrier(0);
  __builtin_amdgcn_s_barrier();
  __builtin_amdgcn_sched_barrier(0);

  const int row = dh * 16 + m;            // x LDS row
  const int mk7 = m & 7;
#pragma unroll
  for (int rr = 0; rr < 8; rr++) {
    const int buf = rr & 1;
#pragma unroll
    for (int s = 0; s < 2; s++) {
#pragma unroll
      for (int nc = 0; nc < 2; nc++) {
        const int c0 = nc * 8 + q * 2;
        float4 f0 = *(const float4*)&xsf[buf][s][row * 64 + ((c0 ^ mk7)) * 4];
        float4 f1 = *(const float4*)&xsf[buf][s][row * 64 + (((c0 + 1) ^ mk7)) * 4];
        bf16x8 xv;
        unsigned* xu = (unsigned*)&xv;
        xu[0] = cvtpk(f0.x, f0.y);
        xu[1] = cvtpk(f0.z, f0.w);
        xu[2] = cvtpk(f1.x, f1.y);
        xu[3] = cvtpk(f1.z, f1.w);
        const int cidx = ((nc * 4 + q) ^ mk7) * 8;
        bf16x8 a0 = *(const bf16x8*)&as_[buf][s][(kh * 32 + m) * 64 + cidx];
        bf16x8 a1 = *(const bf16x8*)&as_[buf][s][(kh * 32 + 16 + m) * 64 + cidx];
        acc0 = __builtin_amdgcn_mfma_f32_16x16x32_bf16(xv, a0, acc0, 0, 0, 0);
        acc1 = __builtin_amdgcn_mfma_f32_16x16x32_bf16(xv, a1, acc1, 0, 0, 0);
      }
    }
    if (rr < 7) {
      __builtin_amdgcn_sched_barrier(0);
      __builtin_amdgcn_s_barrier();       // all waves done reading buf
      __builtin_amdgcn_sched_barrier(0);
      if (rr < 6) {
        STAGE(buf, rr + 2)                // refill buf with pair rr+2
        asm volatile("s_waitcnt vmcnt(8)");  // older 8 (pair rr+1) done
      } else {
        asm volatile("s_waitcnt vmcnt(0)");  // last pair (7) done
      }
      __builtin_amdgcn_sched_barrier(0);
      __builtin_amdgcn_s_barrier();       // pair rr+1 visible to all
      __builtin_amdgcn_sched_barrier(0);
    }
  }
#undef STAGE

  // epilogue: d = dg*32 + dh*16 + q*4 + r; k = kh*32 + {0,16} + m
  const int k0 = kh * 32 + m;
  const int k1 = k0 + 16;
  const float as0 = asum[b * Kv + k0];
  const float as1 = asum[b * Kv + k1];
  float ss0 = 0.f, ss1 = 0.f;
#pragma unroll
  for (int r = 0; r < 4; r++) {
    int d = dg * 32 + dh * 16 + q * 4 + r;
    float v0 = acc0[r] - centers[d * Kv + k0] * as0;
    float v1 = acc1[r] - centers[d * Kv + k1] * as1;
    vlad[((size_t)b * Dv + d) * Kv + k0] = v0;
    vlad[((size_t)b * Dv + d) * Kv + k1] = v1;
    ss0 = fmaf(v0, v0, ss0);
    ss1 = fmaf(v1, v1, ss1);
  }
  ss0 += __shfl_xor(ss0, 16); ss0 += __shfl_xor(ss0, 32);
  ss1 += __shfl_xor(ss1, 16); ss1 += __shfl_xor(ss1, 32);
  if (q == 0) {
    atomicAdd(&colsq[b * Kv + k0], ss0);
    atomicAdd(&colsq[b * Kv + k1], ss1);
  }
}

// ---------------------------------------------------------------------------
// Kernel D: out = vlad * colscale[b,k] * bscale[b]; float4-vectorized.
// ---------------------------------------------------------------------------
__global__ __launch_bounds__(256) void scale_kernel(
    const float* __restrict__ vlad, const float* __restrict__ colsq,
    float* __restrict__ out) {
  const int t = threadIdx.x;
  const size_t i = ((size_t)blockIdx.x * 256 + t) * 4;
  const int b = (int)(i >> 15);
  __shared__ float scs[64];
  __shared__ float bsh;
  if (t < 64) {
    float tot = colsq[b * Kv + t];
    float sc = 1.0f / fmaxf(sqrtf(tot), EPSv);
    scs[t] = sc;
    float contrib = tot * sc * sc;
#pragma unroll
    for (int off = 32; off > 0; off >>= 1) contrib += __shfl_down(contrib, off);
    if (t == 0) bsh = 1.0f / fmaxf(sqrtf(contrib), EPSv);
  }
  __syncthreads();
  float4 v = *(const float4*)&vlad[i];
  const int k = (int)(i & 63);
  float4 o;
  o.x = v.x * scs[k + 0] * bsh;
  o.y = v.y * scs[k + 1] * bsh;
  o.z = v.z * scs[k + 2] * bsh;
  o.w = v.w * scs[k + 3] * bsh;
  *(float4*)&out[i] = o;
}

extern "C" void kernel_launch(void* const* d_in, const int* in_sizes, int n_in,
                              void* d_out, int out_size, void* d_ws, size_t ws_size,
                              hipStream_t stream) {
  const float* x = (const float*)d_in[0];        // [B, D, N]
  const float* w = (const float*)d_in[1];        // [K, D]
  const float* centers = (const float*)d_in[2];  // [D, K]
  float* out = (float*)d_out;                    // [B, D*K]

  char* ws = (char*)d_ws;
  unsigned short* assign = (unsigned short*)ws;               // tiled, 4 MB
  float* vlad = (float*)(ws + 4194304);                       // [B][D][K] fp32, 4 MB
  unsigned short* wbf = (unsigned short*)(ws + 8388608);      // [K][D] bf16, 64 KB
  float* asum = (float*)(ws + 8454144);                       // B*K
  float* colsq = asum + Bv * Kv;                              // B*K

  wconv<<<32, 256, 0, stream>>>(w, wbf, asum);   // also zeros asum+colsq
  fused_scores<<<512, 512, 0, stream>>>(x, wbf, assign, asum);
  vlad_stage<<<512, 256, 0, stream>>>(x, assign, centers, asum, vlad, colsq);
  scale_kernel<<<1024, 256, 0, stream>>>(vlad, colsq, out);
}